// Round 1
// baseline (2169.941 us; speedup 1.0000x reference)
//
#include <hip/hip_runtime.h>
#include <hip/hip_bf16.h>

typedef __hip_bfloat16 bf16;
typedef __attribute__((ext_vector_type(4))) float f32x4;
typedef __attribute__((ext_vector_type(8))) short short8;
typedef __attribute__((ext_vector_type(4))) short short4v;

__device__ __forceinline__ unsigned short f2b(float x) {
  union { float f; unsigned int u; } v; v.f = x;
  unsigned int r = v.u + 0x7fffu + ((v.u >> 16) & 1u);
  return (unsigned short)(r >> 16);
}

// ---------------- weight f32 -> bf16 convert ----------------
__global__ __launch_bounds__(256) void cvt_w_kernel(
    const float* __restrict__ a, const float* __restrict__ b,
    const float* __restrict__ c, const float* __restrict__ d,
    bf16* __restrict__ dst) {
  const int t = blockIdx.x * 256 + threadIdx.x;  // 0..65535, 4 floats each
  const float* srcs[4] = {a, b, c, d};
#pragma unroll
  for (int w = 0; w < 4; ++w) {
    const f32x4 v = *(const f32x4*)(srcs[w] + (size_t)t * 4);
    short4v o;
    o[0] = (short)f2b(v[0]); o[1] = (short)f2b(v[1]);
    o[2] = (short)f2b(v[2]); o[3] = (short)f2b(v[3]);
    *(short4v*)((short*)dst + (size_t)w * 262144 + (size_t)t * 4) = o;
  }
}

// ---------------- GEMM: C[r][c] = sum_k A[r][k] * W[c][k]  (+bias)*scale ----
// BM=128 BN=128 BK=64, 4 waves (2x2), wave tile 64x64 as 4x4 frags of 16x16.
// EPI 0: bf16 scatter [w][h][n][d] (QKV layout)
// EPI 1: f32 row-major [r][512] (final output)
// EPI 2: bf16 scatter transposed [w][h][d][n(pad 64)] (V for PV)
template<bool A_F32, int EPI>
__global__ __launch_bounds__(256) void gemm_bt(const void* __restrict__ Av,
                                               const bf16* __restrict__ W,
                                               const float* __restrict__ bias,
                                               float scale,
                                               void* __restrict__ dst,
                                               int M) {
  __shared__ short As[8192];  // [128][64] bf16, XOR-swizzled 16B slots
  __shared__ short Bs[8192];
  const int tid = threadIdx.x;
  const int lane = tid & 63;
  const int wid = tid >> 6;
  const int wr = wid >> 1, wc = wid & 1;
  const int bn = blockIdx.x;   // N-tile (0..3) fastest: A-panel reused in L2
  const int bm = blockIdx.y;   // M-tile
  const int l15 = lane & 15, lg = lane >> 4;

  f32x4 acc[4][4];
#pragma unroll
  for (int m = 0; m < 4; ++m)
#pragma unroll
    for (int n = 0; n < 4; ++n) acc[m][n] = (f32x4){0.f, 0.f, 0.f, 0.f};

  for (int k0 = 0; k0 < 512; k0 += 64) {
    // ---- stage A (128 rows x 64 k), 1024 groups of 8 elems
#pragma unroll
    for (int i = 0; i < 4; ++i) {
      const int g = tid + 256 * i;
      const int row = g >> 3, k8 = g & 7;
      const int gr = bm * 128 + row;
      short8 u = (short8){0, 0, 0, 0, 0, 0, 0, 0};
      if (A_F32) {
        if (gr < M) {
          const float* ap = (const float*)Av + (size_t)gr * 512 + k0 + k8 * 8;
          const f32x4 lo = *(const f32x4*)ap;
          const f32x4 hi = *(const f32x4*)(ap + 4);
          u[0] = (short)f2b(lo[0]); u[1] = (short)f2b(lo[1]);
          u[2] = (short)f2b(lo[2]); u[3] = (short)f2b(lo[3]);
          u[4] = (short)f2b(hi[0]); u[5] = (short)f2b(hi[1]);
          u[6] = (short)f2b(hi[2]); u[7] = (short)f2b(hi[3]);
        }
      } else {
        if (gr < M)
          u = *(const short8*)((const bf16*)Av + (size_t)gr * 512 + k0 + k8 * 8);
      }
      *(short8*)((char*)As + row * 128 + ((k8 * 16) ^ ((row & 7) << 4))) = u;
    }
    // ---- stage B (weights, always in-bounds: 512x512)
#pragma unroll
    for (int i = 0; i < 4; ++i) {
      const int g = tid + 256 * i;
      const int row = g >> 3, k8 = g & 7;
      const int gr = bn * 128 + row;
      const short8 u = *(const short8*)(W + (size_t)gr * 512 + k0 + k8 * 8);
      *(short8*)((char*)Bs + row * 128 + ((k8 * 16) ^ ((row & 7) << 4))) = u;
    }
    __syncthreads();
#pragma unroll
    for (int s = 0; s < 2; ++s) {
      short8 af[4], bfr[4];
#pragma unroll
      for (int m = 0; m < 4; ++m) {
        const int r = wr * 64 + m * 16 + l15;
        af[m] = *(const short8*)((char*)As + r * 128 +
                                 ((s * 64 + lg * 16) ^ ((r & 7) << 4)));
      }
#pragma unroll
      for (int n = 0; n < 4; ++n) {
        const int r = wc * 64 + n * 16 + l15;
        bfr[n] = *(const short8*)((char*)Bs + r * 128 +
                                  ((s * 64 + lg * 16) ^ ((r & 7) << 4)));
      }
#pragma unroll
      for (int m = 0; m < 4; ++m)
#pragma unroll
        for (int n = 0; n < 4; ++n)
          acc[m][n] = __builtin_amdgcn_mfma_f32_16x16x32_bf16(
              af[m], bfr[n], acc[m][n], 0, 0, 0);
    }
    __syncthreads();
  }
  // ---- epilogue
#pragma unroll
  for (int m = 0; m < 4; ++m) {
#pragma unroll
    for (int n = 0; n < 4; ++n) {
      const int c = bn * 128 + wc * 64 + n * 16 + l15;
      const float bv = bias[c];
#pragma unroll
      for (int reg = 0; reg < 4; ++reg) {
        const int r = bm * 128 + wr * 64 + m * 16 + lg * 4 + reg;
        if (r < M) {
          const float v = (acc[m][n][reg] + bv) * scale;
          if (EPI == 1) {
            ((float*)dst)[(size_t)r * 512 + c] = v;
          } else {
            const int w = r / 49, nt = r % 49;
            const int h = c >> 5, dd = c & 31;
            if (EPI == 0)
              ((bf16*)dst)[(((size_t)w * 16 + h) * 49 + nt) * 32 + dd] =
                  __float2bfloat16(v);
            else  // EPI == 2: V transposed, n padded to 64 (pad pre-zeroed)
              ((bf16*)dst)[(((size_t)w * 16 + h) * 32 + dd) * 64 + nt] =
                  __float2bfloat16(v);
          }
        }
      }
    }
  }
}

// ---------------- windowed attention: one block per window, wave per head ---
__global__ __launch_bounds__(256) void attn_win(const bf16* __restrict__ q_ws,
                                                const bf16* __restrict__ k_ws,
                                                const bf16* __restrict__ vT_ws,
                                                const float* __restrict__ btab,
                                                const float* __restrict__ mask,
                                                bf16* __restrict__ x_ws,
                                                int wstart) {
  __shared__ float smask[2401];      // 49x49 mask for this window
  __shared__ float stabT[16 * 169];  // bias table transposed [h][t]
  __shared__ short sP[4][4096];      // per-wave P (64x64 bf16, swizzled)
  const int tid = threadIdx.x;
  const int lane = tid & 63, wid = tid >> 6;
  const int l15 = lane & 15, lg = lane >> 4;
  const int wl = blockIdx.x;
  const int wg = wstart + wl;
  const float NEG = -3.0e38f;

  for (int i = tid; i < 2401; i += 256)
    smask[i] = mask[(size_t)(wg & 1023) * 2401 + i];
  for (int i = tid; i < 2704; i += 256)
    stabT[(i & 15) * 169 + (i >> 4)] = btab[i];  // btab layout [t][h]
  __syncthreads();

  short* Pl = sP[wid];

#pragma unroll 1
  for (int hh = 0; hh < 4; ++hh) {
    const int h = wid * 4 + hh;
    const size_t base = ((size_t)wl * 16 + h) * 1568;  // 49*32

    // Q A-frags / K B-frags (identical read pattern, K dim = d = 32)
    short8 qf[4], kf[4];
    const short8 z8 = (short8){0, 0, 0, 0, 0, 0, 0, 0};
#pragma unroll
    for (int m = 0; m < 4; ++m) {
      const int r = m * 16 + l15;
      qf[m] = (r < 49) ? *(const short8*)(q_ws + base + r * 32 + lg * 8) : z8;
      kf[m] = (r < 49) ? *(const short8*)(k_ws + base + r * 32 + lg * 8) : z8;
    }
    f32x4 lc[4][4];
#pragma unroll
    for (int m = 0; m < 4; ++m)
#pragma unroll
      for (int n = 0; n < 4; ++n)
        lc[m][n] = __builtin_amdgcn_mfma_f32_16x16x32_bf16(
            qf[m], kf[n], (f32x4){0.f, 0.f, 0.f, 0.f}, 0, 0, 0);

    // + relative position bias + mask; pad cols/rows -> NEG
    int aj[4], bj[4];
#pragma unroll
    for (int n = 0; n < 4; ++n) {
      const int cc = n * 16 + l15;
      aj[n] = cc / 7; bj[n] = cc % 7;
    }
#pragma unroll
    for (int m = 0; m < 4; ++m) {
#pragma unroll
      for (int reg = 0; reg < 4; ++reg) {
        const int i = m * 16 + lg * 4 + reg;
        const int ai = i / 7, bi2 = i % 7;
#pragma unroll
        for (int n = 0; n < 4; ++n) {
          const int cc = n * 16 + l15;
          if (i < 49 && cc < 49) {
            const int t = (ai - aj[n] + 6) * 13 + (bi2 - bj[n] + 6);
            lc[m][n][reg] += stabT[h * 169 + t] + smask[i * 49 + cc];
          } else {
            lc[m][n][reg] = NEG;
          }
        }
      }
    }

    // softmax over row (cols spread over 4 n-frags x 16 lanes of same lg)
#pragma unroll
    for (int m = 0; m < 4; ++m) {
#pragma unroll
      for (int reg = 0; reg < 4; ++reg) {
        float vmax = fmaxf(fmaxf(lc[m][0][reg], lc[m][1][reg]),
                           fmaxf(lc[m][2][reg], lc[m][3][reg]));
#pragma unroll
        for (int off = 1; off < 16; off <<= 1)
          vmax = fmaxf(vmax, __shfl_xor(vmax, off, 64));
        float e[4];
        float ssum = 0.f;
#pragma unroll
        for (int n = 0; n < 4; ++n) {
          const int cc = n * 16 + l15;
          const float ev = (cc < 49) ? __expf(lc[m][n][reg] - vmax) : 0.f;
          e[n] = ev; ssum += ev;
        }
#pragma unroll
        for (int off = 1; off < 16; off <<= 1) ssum += __shfl_xor(ssum, off, 64);
        const float inv = 1.f / ssum;
        const int i = m * 16 + lg * 4 + reg;
#pragma unroll
        for (int n = 0; n < 4; ++n) {
          const int cc = n * 16 + l15;
          *(unsigned short*)((char*)Pl + i * 128 +
                             ((2 * cc) ^ ((i & 7) << 4))) = f2b(e[n] * inv);
        }
      }
    }

    // PV: X(64x32) = P(64x64) @ V(64x32), K = 64 in two 32-steps
    f32x4 xacc[4][2];
#pragma unroll
    for (int m = 0; m < 4; ++m)
#pragma unroll
      for (int n = 0; n < 2; ++n) xacc[m][n] = (f32x4){0.f, 0.f, 0.f, 0.f};
    const size_t vbase = ((size_t)wl * 16 + h) * 2048;  // 32*64
#pragma unroll
    for (int s = 0; s < 2; ++s) {
      short8 pf[4], vf[2];
#pragma unroll
      for (int m = 0; m < 4; ++m) {
        const int i = m * 16 + l15;
        pf[m] = *(const short8*)((char*)Pl + i * 128 +
                                 ((s * 64 + lg * 16) ^ ((i & 7) << 4)));
      }
#pragma unroll
      for (int n = 0; n < 2; ++n) {
        const int dd = n * 16 + l15;
        vf[n] = *(const short8*)(vT_ws + vbase + dd * 64 + s * 32 + lg * 8);
      }
#pragma unroll
      for (int m = 0; m < 4; ++m)
#pragma unroll
        for (int n = 0; n < 2; ++n)
          xacc[m][n] = __builtin_amdgcn_mfma_f32_16x16x32_bf16(
              pf[m], vf[n], xacc[m][n], 0, 0, 0);
    }
    // store X rows < 49 as bf16 row-major [wl*49+i][512]
#pragma unroll
    for (int m = 0; m < 4; ++m) {
#pragma unroll
      for (int n = 0; n < 2; ++n) {
#pragma unroll
        for (int reg = 0; reg < 4; ++reg) {
          const int i = m * 16 + lg * 4 + reg;
          if (i < 49) {
            const int dd = n * 16 + l15;
            x_ws[((size_t)wl * 49 + i) * 512 + h * 32 + dd] =
                __float2bfloat16(xacc[m][n][reg]);
          }
        }
      }
    }
  }
}

extern "C" void kernel_launch(void* const* d_in, const int* in_sizes, int n_in,
                              void* d_out, int out_size, void* d_ws,
                              size_t ws_size, hipStream_t stream) {
  const float* lf   = (const float*)d_in[0];
  const float* gfx  = (const float*)d_in[1];
  const float* mask = (const float*)d_in[2];
  const float* btab = (const float*)d_in[3];
  const float* Wk = (const float*)d_in[4];  const float* bk = (const float*)d_in[5];
  const float* Wq = (const float*)d_in[6];  const float* bq = (const float*)d_in[7];
  const float* Wv = (const float*)d_in[8];  const float* bv = (const float*)d_in[9];
  const float* Wp = (const float*)d_in[10]; const float* bp = (const float*)d_in[11];
  float* out = (float*)d_out;

  char* ws = (char*)d_ws;
  bf16* wbf = (bf16*)ws;                       // 4 x 262144 bf16 = 2 MB
  const size_t woff = (size_t)4 * 262144 * sizeof(bf16);
  const size_t PW_Q = 49 * 32 * 16 * 2;        // 50176 (per window, q or k)
  const size_t PW_V = 32 * 64 * 16 * 2;        // 65536 (vT, n padded to 64)
  const size_t PW_X = 49 * 512 * 2;            // 50176
  const size_t PW = PW_Q * 2 + PW_V + PW_X;    // 216064
  size_t avail = ws_size > woff ? ws_size - woff : 0;
  int CH = (int)(avail / PW);
  if (CH > 4096) CH = 4096;
  if (CH < 1) CH = 1;

  bf16* q_ws  = (bf16*)(ws + woff);
  bf16* k_ws  = q_ws + (size_t)CH * 25088;
  bf16* vT_ws = k_ws + (size_t)CH * 25088;
  bf16* x_ws  = vT_ws + (size_t)CH * 32768;

  cvt_w_kernel<<<256, 256, 0, stream>>>(Wk, Wq, Wv, Wp, wbf);

  const float qscale = 0.17677669529663687f;  // 1/sqrt(32)
  for (int wstart = 0; wstart < 4096; wstart += CH) {
    const int nwin = (4096 - wstart < CH) ? (4096 - wstart) : CH;
    const int M = nwin * 49;
    const int gy = (M + 127) / 128;
    hipMemsetAsync(vT_ws, 0, (size_t)nwin * PW_V, stream);
    gemm_bt<true, 0><<<dim3(4, gy), 256, 0, stream>>>(
        lf + (size_t)wstart * 25088, wbf + 0 * 262144, bk, 1.0f, k_ws, M);
    gemm_bt<true, 0><<<dim3(4, gy), 256, 0, stream>>>(
        gfx + (size_t)wstart * 25088, wbf + 1 * 262144, bq, qscale, q_ws, M);
    gemm_bt<true, 2><<<dim3(4, gy), 256, 0, stream>>>(
        lf + (size_t)wstart * 25088, wbf + 2 * 262144, bv, 1.0f, vT_ws, M);
    attn_win<<<nwin, 256, 0, stream>>>(q_ws, k_ws, vT_ws, btab, mask, x_ws,
                                       wstart);
    gemm_bt<false, 1><<<dim3(4, gy), 256, 0, stream>>>(
        x_ws, wbf + 3 * 262144, bp, 1.0f, out + (size_t)wstart * 25088, M);
  }
}

// Round 2
// 1837.446 us; speedup vs baseline: 1.1810x; 1.1810x over previous
//
#include <hip/hip_runtime.h>
#include <hip/hip_bf16.h>

typedef __hip_bfloat16 bf16;
typedef __attribute__((ext_vector_type(4))) float f32x4;
typedef __attribute__((ext_vector_type(8))) short short8;
typedef __attribute__((ext_vector_type(4))) short short4v;

#define NEGBIG (-3.0e38f)

__device__ __forceinline__ unsigned short f2b(float x) {
  union { float f; unsigned int u; } v; v.f = x;
  unsigned int r = v.u + 0x7fffu + ((v.u >> 16) & 1u);
  return (unsigned short)(r >> 16);
}

__device__ __forceinline__ void gl16(const void* g, void* l) {
  __builtin_amdgcn_global_load_lds(
      (const __attribute__((address_space(1))) unsigned int*)g,
      (__attribute__((address_space(3))) unsigned int*)l, 16, 0, 0);
}

// ---------------- weight f32 -> bf16 (row-major) ----------------
__global__ __launch_bounds__(256) void cvt_w_kernel(
    const float* __restrict__ a, const float* __restrict__ b,
    const float* __restrict__ c, const float* __restrict__ d,
    bf16* __restrict__ dst) {
  const int t = blockIdx.x * 256 + threadIdx.x;  // 0..65535, 4 floats each
  const float* srcs[4] = {a, b, c, d};
#pragma unroll
  for (int w = 0; w < 4; ++w) {
    const f32x4 v = *(const f32x4*)(srcs[w] + (size_t)t * 4);
    short4v o;
    o[0] = (short)f2b(v[0]); o[1] = (short)f2b(v[1]);
    o[2] = (short)f2b(v[2]); o[3] = (short)f2b(v[3]);
    *(short4v*)((short*)dst + (size_t)w * 262144 + (size_t)t * 4) = o;
  }
}

// ---------------- activation f32 -> bf16 (row-major [M][512]) -------------
__global__ __launch_bounds__(256) void cvt_a(const float* __restrict__ src,
                                             short* __restrict__ dst, int M) {
  const int g = blockIdx.x * 256 + threadIdx.x;  // row*64 + k8
  const int row = g >> 6, k8 = g & 63;
  if (row >= M) return;
  const float* sp = src + (size_t)row * 512 + k8 * 8;
  const f32x4 lo = *(const f32x4*)sp;
  const f32x4 hi = *(const f32x4*)(sp + 4);
  short8 u;
  u[0] = (short)f2b(lo[0]); u[1] = (short)f2b(lo[1]);
  u[2] = (short)f2b(lo[2]); u[3] = (short)f2b(lo[3]);
  u[4] = (short)f2b(hi[0]); u[5] = (short)f2b(hi[1]);
  u[6] = (short)f2b(hi[2]); u[7] = (short)f2b(hi[3]);
  *(short8*)(dst + (size_t)row * 512 + k8 * 8) = u;
}

// ---- bias table -> per-(head, mfma-frag-element) layout, pads = NEGBIG ----
__global__ __launch_bounds__(256) void prep_rpbL(const float* __restrict__ btab,
                                                 float* __restrict__ rpbL) {
  const int g = blockIdx.x * 256 + threadIdx.x;  // (h*16+mn)*64+lane, 16384
  const int lane = g & 63, mn = (g >> 6) & 15, h = g >> 10;
  const int m = mn >> 2, n = mn & 3, l15 = lane & 15, lg = lane >> 4;
  const int cc = n * 16 + l15;
  const int aj = cc / 7, bj = cc % 7;
  f32x4 o;
#pragma unroll
  for (int reg = 0; reg < 4; ++reg) {
    const int i = m * 16 + lg * 4 + reg;
    if (i < 49 && cc < 49) {
      const int t = (i / 7 - aj + 6) * 13 + (i % 7 - bj + 6);
      o[reg] = btab[t * 16 + h];
    } else {
      o[reg] = NEGBIG;
    }
  }
  ((f32x4*)rpbL)[g] = o;
}

// ---- mask -> per-(window, frag-element) layout, pads = 0 ----
__global__ __launch_bounds__(256) void prep_maskL(const float* __restrict__ mask,
                                                  float* __restrict__ maskL) {
  const int g = blockIdx.x * 256 + threadIdx.x;  // (wm*16+mn)*64+lane, 1048576
  const int lane = g & 63, mn = (g >> 6) & 15, wm = g >> 10;
  const int m = mn >> 2, n = mn & 3, l15 = lane & 15, lg = lane >> 4;
  const int cc = n * 16 + l15;
  f32x4 o;
#pragma unroll
  for (int reg = 0; reg < 4; ++reg) {
    const int i = m * 16 + lg * 4 + reg;
    o[reg] = (i < 49 && cc < 49) ? mask[(size_t)wm * 2401 + i * 49 + cc] : 0.f;
  }
  ((f32x4*)maskL)[g] = o;
}

// ---------------- GEMM: C[r][c] = sum_k A[r][k] * W[c][k]  (+bias)*scale ----
// A,B bf16 row-major staged via global_load_lds (m97 structure).
// EPI 0: bf16 scatter [w][h][n][d]; 1: f32 [r][512]; 2: vT scatter;
// 3: dual KV (bn<4 -> EPI0 to dst, else EPI2 to dst2 with Bbf2/bias2)
template <int EPI>
__global__ __launch_bounds__(256) void gemm2(
    const short* __restrict__ Abf, const short* __restrict__ Bbf,
    const short* __restrict__ Bbf2, const float* __restrict__ bias,
    const float* __restrict__ bias2, float scale, void* __restrict__ dst,
    void* __restrict__ dst2, int M) {
  __shared__ short As[8192];  // [128 rows][64 k] bf16, linear
  __shared__ short Bs[8192];
  const int tid = threadIdx.x, lane = tid & 63, wid = tid >> 6;
  const int wr = wid >> 1, wc = wid & 1, l15 = lane & 15, lg = lane >> 4;
  const int bn = blockIdx.x, bm = blockIdx.y;
  const bool isV = (EPI == 3) && (bn >= 4);
  const int bnl = isV ? bn - 4 : bn;
  const char* Ab = (const char*)Abf;
  const char* Bb = (const char*)(isV ? Bbf2 : Bbf);
  const float* bb = isV ? bias2 : bias;
  f32x4 acc[4][4];
#pragma unroll
  for (int m = 0; m < 4; ++m)
#pragma unroll
    for (int n = 0; n < 4; ++n) acc[m][n] = (f32x4){0.f, 0.f, 0.f, 0.f};

  const int tr = tid >> 3;          // row-in-group 0..31
  const int tcol = (tid & 7) * 16;  // byte col within 128B row-slice

  for (int k0 = 0; k0 < 512; k0 += 64) {
#pragma unroll
    for (int i = 0; i < 4; ++i) {
      gl16(Ab + (size_t)(bm * 128 + tr + i * 32) * 1024 + k0 * 2 + tcol,
           (char*)As + tid * 16 + i * 4096);
      gl16(Bb + (size_t)(bnl * 128 + tr + i * 32) * 1024 + k0 * 2 + tcol,
           (char*)Bs + tid * 16 + i * 4096);
    }
    __syncthreads();
#pragma unroll
    for (int s = 0; s < 2; ++s) {
      short8 af[4], bfr[4];
#pragma unroll
      for (int m = 0; m < 4; ++m)
        af[m] = *(const short8*)((char*)As + (wr * 64 + m * 16 + l15) * 128 +
                                 s * 64 + lg * 16);
#pragma unroll
      for (int n = 0; n < 4; ++n)
        bfr[n] = *(const short8*)((char*)Bs + (wc * 64 + n * 16 + l15) * 128 +
                                  s * 64 + lg * 16);
#pragma unroll
      for (int m = 0; m < 4; ++m)
#pragma unroll
        for (int n = 0; n < 4; ++n)
          acc[m][n] = __builtin_amdgcn_mfma_f32_16x16x32_bf16(
              af[m], bfr[n], acc[m][n], 0, 0, 0);
    }
    __syncthreads();
  }

  const int eep = (EPI == 3) ? (isV ? 2 : 0) : EPI;
  void* dp = isV ? dst2 : dst;
#pragma unroll
  for (int m = 0; m < 4; ++m) {
#pragma unroll
    for (int n = 0; n < 4; ++n) {
      const int c = bnl * 128 + wc * 64 + n * 16 + l15;
      const float bv = bb[c];
#pragma unroll
      for (int reg = 0; reg < 4; ++reg) {
        const int r = bm * 128 + wr * 64 + m * 16 + lg * 4 + reg;
        if (r < M) {
          const float v = (acc[m][n][reg] + bv) * scale;
          if (eep == 1) {
            ((float*)dp)[(size_t)r * 512 + c] = v;
          } else {
            const int w = r / 49, nt = r - w * 49;
            const int hh = c >> 5, ddm = c & 31;
            if (eep == 0)
              ((bf16*)dp)[(((size_t)w * 16 + hh) * 49 + nt) * 32 + ddm] =
                  __float2bfloat16(v);
            else
              ((bf16*)dp)[(((size_t)w * 16 + hh) * 32 + ddm) * 64 + nt] =
                  __float2bfloat16(v);
          }
        }
      }
    }
  }
}

// ---------------- windowed attention: 1 head per wave, no barriers ---------
__global__ __launch_bounds__(256) void attn_win2(
    const bf16* __restrict__ q_ws, const bf16* __restrict__ k_ws,
    const bf16* __restrict__ vT_ws, const float* __restrict__ rpbL,
    const float* __restrict__ maskL, bf16* __restrict__ x_ws, int wstart) {
  __shared__ short sP[4][4096];  // 8 KB per wave: P (64x128B) then X (64x80B)
  const int tid = threadIdx.x, lane = tid & 63, wid = tid >> 6;
  const int l15 = lane & 15, lg = lane >> 4;
  const int wl = blockIdx.x;
  const int h = blockIdx.y * 4 + wid;
  const int wg = wstart + wl;
  char* Pl = (char*)sP[wid];
  const size_t base = ((size_t)wl * 16 + h) * 1568;
  const short8 z8 = (short8){0, 0, 0, 0, 0, 0, 0, 0};

  short8 qf[4], kf[4];
#pragma unroll
  for (int m = 0; m < 4; ++m) {
    const int r = m * 16 + l15;
    qf[m] = (r < 49) ? *(const short8*)(q_ws + base + r * 32 + lg * 8) : z8;
    kf[m] = (r < 49) ? *(const short8*)(k_ws + base + r * 32 + lg * 8) : z8;
  }
  f32x4 lc[4][4];
#pragma unroll
  for (int m = 0; m < 4; ++m)
#pragma unroll
    for (int n = 0; n < 4; ++n)
      lc[m][n] = __builtin_amdgcn_mfma_f32_16x16x32_bf16(
          qf[m], kf[n], (f32x4){0.f, 0.f, 0.f, 0.f}, 0, 0, 0);

  // + bias (pads pre-baked to NEGBIG) + mask, both in frag layout
  const f32x4* rbp = (const f32x4*)rpbL + (size_t)h * 1024 + lane;
  const f32x4* mkp = (const f32x4*)maskL + (size_t)(wg & 1023) * 1024 + lane;
#pragma unroll
  for (int m = 0; m < 4; ++m)
#pragma unroll
    for (int n = 0; n < 4; ++n) {
      const int mn = m * 4 + n;
      lc[m][n] += rbp[mn * 64] + mkp[mn * 64];
    }

  // softmax over rows; cols live in 4 n-frags x 16 l15-lanes (same lg)
#pragma unroll
  for (int m = 0; m < 4; ++m) {
#pragma unroll
    for (int reg = 0; reg < 4; ++reg) {
      float vmax = fmaxf(fmaxf(lc[m][0][reg], lc[m][1][reg]),
                         fmaxf(lc[m][2][reg], lc[m][3][reg]));
#pragma unroll
      for (int off = 1; off < 16; off <<= 1)
        vmax = fmaxf(vmax, __shfl_xor(vmax, off, 64));
      float e[4], ssum = 0.f;
#pragma unroll
      for (int n = 0; n < 4; ++n) {
        e[n] = __expf(lc[m][n][reg] - vmax);
        ssum += e[n];
      }
#pragma unroll
      for (int off = 1; off < 16; off <<= 1) ssum += __shfl_xor(ssum, off, 64);
      const float inv = __builtin_amdgcn_rcpf(ssum);
      const int i = m * 16 + lg * 4 + reg;
#pragma unroll
      for (int n = 0; n < 4; ++n) {
        const int cc = n * 16 + l15;
        *(unsigned short*)(Pl + i * 128 + ((2 * cc) ^ ((i & 7) << 4))) =
            f2b(e[n] * inv);
      }
    }
  }

  // PV: X(64x32) = P(64x64) @ V(64x32); V pad tokens (>=49) zeroed in-reg
  f32x4 xacc[4][2];
#pragma unroll
  for (int m = 0; m < 4; ++m)
#pragma unroll
    for (int n = 0; n < 2; ++n) xacc[m][n] = (f32x4){0.f, 0.f, 0.f, 0.f};
  const size_t vbase = ((size_t)wl * 16 + h) * 2048;
#pragma unroll
  for (int s = 0; s < 2; ++s) {
    short8 pf[4], vf[2];
#pragma unroll
    for (int m = 0; m < 4; ++m) {
      const int i = m * 16 + l15;
      pf[m] = *(const short8*)(Pl + i * 128 +
                               ((s * 64 + lg * 16) ^ ((i & 7) << 4)));
    }
#pragma unroll
    for (int n = 0; n < 2; ++n) {
      const int dd = n * 16 + l15;
      short8 vv = *(const short8*)(vT_ws + vbase + dd * 64 + s * 32 + lg * 8);
      if (s == 1) {
        if (lg == 3) vv = z8;
        else if (lg == 2) {
          vv[1] = 0; vv[2] = 0; vv[3] = 0; vv[4] = 0;
          vv[5] = 0; vv[6] = 0; vv[7] = 0;
        }
      }
      vf[n] = vv;
    }
#pragma unroll
    for (int m = 0; m < 4; ++m)
#pragma unroll
      for (int n = 0; n < 2; ++n)
        xacc[m][n] = __builtin_amdgcn_mfma_f32_16x16x32_bf16(
            pf[m], vf[n], xacc[m][n], 0, 0, 0);
  }

  // stage X in LDS (64 rows x 80B, swizzled), then 64B-line coalesced stores
#pragma unroll
  for (int m = 0; m < 4; ++m)
#pragma unroll
    for (int n = 0; n < 2; ++n)
#pragma unroll
      for (int reg = 0; reg < 4; ++reg) {
        const int i = m * 16 + lg * 4 + reg;
        const int dd = n * 16 + l15;
        *(unsigned short*)(Pl + i * 80 + ((2 * dd) ^ ((i & 3) << 4))) =
            f2b(xacc[m][n][reg]);
      }
#pragma unroll
  for (int g = 0; g < 4; ++g) {
    const int row = g * 16 + (lane >> 2);
    if (row < 49) {
      const short8 xv = *(const short8*)(
          Pl + row * 80 + (((lane & 3) * 16) ^ ((row & 3) << 4)));
      *(short8*)(x_ws + ((size_t)wl * 49 + row) * 512 + h * 32 +
                 (lane & 3) * 8) = xv;
    }
  }
}

extern "C" void kernel_launch(void* const* d_in, const int* in_sizes, int n_in,
                              void* d_out, int out_size, void* d_ws,
                              size_t ws_size, hipStream_t stream) {
  const float* lf   = (const float*)d_in[0];
  const float* gfx  = (const float*)d_in[1];
  const float* mask = (const float*)d_in[2];
  const float* btab = (const float*)d_in[3];
  const float* Wk = (const float*)d_in[4];  const float* bk = (const float*)d_in[5];
  const float* Wq = (const float*)d_in[6];  const float* bq = (const float*)d_in[7];
  const float* Wv = (const float*)d_in[8];  const float* bv = (const float*)d_in[9];
  const float* Wp = (const float*)d_in[10]; const float* bp = (const float*)d_in[11];
  float* out = (float*)d_out;

  char* ws = (char*)d_ws;
  short* wbf = (short*)ws;  // 4 x 512x512 bf16 = 2 MB
  size_t off = (size_t)4 * 262144 * 2;
  float* rpbL = (float*)(ws + off); off += (size_t)16 * 4096 * 4;     // 256 KB
  float* maskL = (float*)(ws + off); off += (size_t)1024 * 4096 * 4;  // 16 MB

  const size_t perw = 2 * 49 * 1024 + 2 * 50176 + 65536;  // 266240 B/window
  size_t avail = (ws_size > off + 65536) ? ws_size - off - 65536 : 0;
  int CH = (int)((avail > 300000) ? (avail - 262144) / perw : 1);
  if (CH > 4096) CH = 4096;
  if (CH < 1) CH = 1;
  const int RWS = ((CH * 49 + 127) / 128) * 128;

  short* Al = (short*)(ws + off); off += (size_t)RWS * 1024;
  short* Ag = (short*)(ws + off); off += (size_t)RWS * 1024;
  bf16* q_ws = (bf16*)(ws + off); off += (size_t)CH * 50176;
  bf16* k_ws = (bf16*)(ws + off); off += (size_t)CH * 50176;
  bf16* vT_ws = (bf16*)(ws + off); off += (size_t)CH * 65536;
  bf16* x_ws = (bf16*)Al;  // alias: Al is dead once KV-GEMM finishes

  cvt_w_kernel<<<256, 256, 0, stream>>>(Wk, Wq, Wv, Wp, (bf16*)wbf);
  prep_rpbL<<<64, 256, 0, stream>>>(btab, rpbL);
  prep_maskL<<<4096, 256, 0, stream>>>(mask, maskL);

  const float qscale = 0.17677669529663687f;  // 1/sqrt(32)
  for (int wstart = 0; wstart < 4096; wstart += CH) {
    const int nwin = (4096 - wstart < CH) ? (4096 - wstart) : CH;
    const int M = nwin * 49;
    const int gy = (M + 127) / 128;
    const int cg = (M * 64 + 255) / 256;
    cvt_a<<<cg, 256, 0, stream>>>(lf + (size_t)wstart * 25088, Al, M);
    cvt_a<<<cg, 256, 0, stream>>>(gfx + (size_t)wstart * 25088, Ag, M);
    gemm2<3><<<dim3(8, gy), 256, 0, stream>>>(
        Al, wbf, wbf + 2 * 262144, bk, bv, 1.0f, k_ws, vT_ws, M);
    gemm2<0><<<dim3(4, gy), 256, 0, stream>>>(
        Ag, wbf + 262144, nullptr, bq, nullptr, qscale, q_ws, nullptr, M);
    attn_win2<<<dim3(nwin, 4), 256, 0, stream>>>(q_ws, k_ws, vT_ws, rpbL,
                                                 maskL, x_ws, wstart);
    gemm2<1><<<dim3(4, gy), 256, 0, stream>>>(
        (const short*)x_ws, wbf + 3 * 262144, nullptr, bp, nullptr, 1.0f,
        out + (size_t)wstart * 25088, nullptr, M);
  }
}

// Round 3
// 1627.286 us; speedup vs baseline: 1.3335x; 1.1291x over previous
//
#include <hip/hip_runtime.h>
#include <hip/hip_bf16.h>

typedef __hip_bfloat16 bf16;
typedef __attribute__((ext_vector_type(4))) float f32x4;
typedef __attribute__((ext_vector_type(8))) short short8;
typedef __attribute__((ext_vector_type(4))) short short4v;

#define NEGBIG (-3.0e38f)

__device__ __forceinline__ unsigned short f2b(float x) {
  union { float f; unsigned int u; } v; v.f = x;
  unsigned int r = v.u + 0x7fffu + ((v.u >> 16) & 1u);
  return (unsigned short)(r >> 16);
}

__device__ __forceinline__ void gl16(const void* g, void* l) {
  __builtin_amdgcn_global_load_lds(
      (const __attribute__((address_space(1))) unsigned int*)g,
      (__attribute__((address_space(3))) unsigned int*)l, 16, 0, 0);
}

// bijective XCD-grouping swizzle (m204): contiguous tile range per XCD
__device__ __forceinline__ int xcd_swz(int orig, int nwg) {
  const int q = nwg >> 3, r = nwg & 7;
  const int xcd = orig & 7;
  const int base = (xcd < r) ? xcd * (q + 1) : r * (q + 1) + (xcd - r) * q;
  return base + (orig >> 3);
}

// ---------------- weight f32 -> bf16 (row-major) ----------------
__global__ __launch_bounds__(256) void cvt_w_kernel(
    const float* __restrict__ a, const float* __restrict__ b,
    const float* __restrict__ c, const float* __restrict__ d,
    bf16* __restrict__ dst) {
  const int t = blockIdx.x * 256 + threadIdx.x;
  const float* srcs[4] = {a, b, c, d};
#pragma unroll
  for (int w = 0; w < 4; ++w) {
    const f32x4 v = *(const f32x4*)(srcs[w] + (size_t)t * 4);
    short4v o;
    o[0] = (short)f2b(v[0]); o[1] = (short)f2b(v[1]);
    o[2] = (short)f2b(v[2]); o[3] = (short)f2b(v[3]);
    *(short4v*)((short*)dst + (size_t)w * 262144 + (size_t)t * 4) = o;
  }
}

// ---------------- activation f32 -> bf16 (row-major [M][512]) -------------
__global__ __launch_bounds__(256) void cvt_a(const float* __restrict__ src,
                                             short* __restrict__ dst, int M) {
  const int g = blockIdx.x * 256 + threadIdx.x;
  const int row = g >> 6, k8 = g & 63;
  if (row >= M) return;
  const float* sp = src + (size_t)row * 512 + k8 * 8;
  const f32x4 lo = *(const f32x4*)sp;
  const f32x4 hi = *(const f32x4*)(sp + 4);
  short8 u;
  u[0] = (short)f2b(lo[0]); u[1] = (short)f2b(lo[1]);
  u[2] = (short)f2b(lo[2]); u[3] = (short)f2b(lo[3]);
  u[4] = (short)f2b(hi[0]); u[5] = (short)f2b(hi[1]);
  u[6] = (short)f2b(hi[2]); u[7] = (short)f2b(hi[3]);
  *(short8*)(dst + (size_t)row * 512 + k8 * 8) = u;
}

// ---- bias table -> per-(head, frag-element) layout, pads = NEGBIG ----
__global__ __launch_bounds__(256) void prep_rpbL(const float* __restrict__ btab,
                                                 float* __restrict__ rpbL) {
  const int g = blockIdx.x * 256 + threadIdx.x;
  const int lane = g & 63, mn = (g >> 6) & 15, h = g >> 10;
  const int m = mn >> 2, n = mn & 3, l15 = lane & 15, lg = lane >> 4;
  const int cc = n * 16 + l15;
  const int aj = cc / 7, bj = cc % 7;
  f32x4 o;
#pragma unroll
  for (int reg = 0; reg < 4; ++reg) {
    const int i = m * 16 + lg * 4 + reg;
    if (i < 49 && cc < 49) {
      const int t = (i / 7 - aj + 6) * 13 + (i % 7 - bj + 6);
      o[reg] = btab[t * 16 + h];
    } else {
      o[reg] = NEGBIG;
    }
  }
  ((f32x4*)rpbL)[g] = o;
}

// ---- mask -> per-(window, frag-element) layout, pads = 0 ----
__global__ __launch_bounds__(256) void prep_maskL(const float* __restrict__ mask,
                                                  float* __restrict__ maskL) {
  const int g = blockIdx.x * 256 + threadIdx.x;
  const int lane = g & 63, mn = (g >> 6) & 15, wm = g >> 10;
  const int m = mn >> 2, n = mn & 3, l15 = lane & 15, lg = lane >> 4;
  const int cc = n * 16 + l15;
  f32x4 o;
#pragma unroll
  for (int reg = 0; reg < 4; ++reg) {
    const int i = m * 16 + lg * 4 + reg;
    o[reg] = (i < 49 && cc < 49) ? mask[(size_t)wm * 2401 + i * 49 + cc] : 0.f;
  }
  ((f32x4*)maskL)[g] = o;
}

// ---------------- fused KQV GEMM --------------------------------------------
// 1-D grid of 12*gy blocks, XCD-swizzled; bn class: 0..3=K, 4..7=Q, 8..11=V^T.
// K/Q: C[r][c] = sum_k A[r][k] W[c][k]  -> [w][h][nt][dd] bf16
// V^T: C[ch][tok] = sum_k W[ch][k] A[tok][k] -> [w][h][dd][nt(pad64)] bf16
__global__ __launch_bounds__(256) void gemm_kqv(
    const short* __restrict__ Al, const short* __restrict__ Ag,
    const short* __restrict__ wbf, const float* __restrict__ bk,
    const float* __restrict__ bq, const float* __restrict__ bv, float qscale,
    bf16* __restrict__ k_ws, bf16* __restrict__ q_ws, bf16* __restrict__ vT_ws,
    int M) {
  __shared__ short As[8192];  // [128 rows][64 k] bf16, linear
  __shared__ short Bs[8192];
  const int nwg = gridDim.x;
  const int t = xcd_swz(blockIdx.x, nwg);
  const int bn = t % 12, bm = t / 12;
  const int cls = bn >> 2, bnl = bn & 3;
  const int tid = threadIdx.x, lane = tid & 63, wid = tid >> 6;
  const int wr = wid >> 1, wc = wid & 1, l15 = lane & 15, lg = lane >> 4;
  const char* Ab = (const char*)((cls == 1) ? Ag : Al);
  const char* Bb = (const char*)(wbf + (size_t)cls * 262144);

  f32x4 acc[4][4];
#pragma unroll
  for (int m = 0; m < 4; ++m)
#pragma unroll
    for (int n = 0; n < 4; ++n) acc[m][n] = (f32x4){0.f, 0.f, 0.f, 0.f};

  const int tr = tid >> 3;
  const int tcol = (tid & 7) * 16;
  const char* fa = (cls == 2) ? (const char*)Bs : (const char*)As;
  const char* fb = (cls == 2) ? (const char*)As : (const char*)Bs;

  for (int k0 = 0; k0 < 512; k0 += 64) {
#pragma unroll
    for (int i = 0; i < 4; ++i) {
      gl16(Ab + (size_t)(bm * 128 + tr + i * 32) * 1024 + k0 * 2 + tcol,
           (char*)As + tid * 16 + i * 4096);
      gl16(Bb + (size_t)(bnl * 128 + tr + i * 32) * 1024 + k0 * 2 + tcol,
           (char*)Bs + tid * 16 + i * 4096);
    }
    __syncthreads();
#pragma unroll
    for (int s = 0; s < 2; ++s) {
      short8 af[4], bfr[4];
#pragma unroll
      for (int m = 0; m < 4; ++m)
        af[m] = *(const short8*)(fa + (wr * 64 + m * 16 + l15) * 128 + s * 64 +
                                 lg * 16);
#pragma unroll
      for (int n = 0; n < 4; ++n)
        bfr[n] = *(const short8*)(fb + (wc * 64 + n * 16 + l15) * 128 + s * 64 +
                                  lg * 16);
#pragma unroll
      for (int m = 0; m < 4; ++m)
#pragma unroll
        for (int n = 0; n < 4; ++n)
          acc[m][n] = __builtin_amdgcn_mfma_f32_16x16x32_bf16(
              af[m], bfr[n], acc[m][n], 0, 0, 0);
    }
    __syncthreads();
  }

  if (cls == 2) {  // V^T epilogue: rows=channels, cols=tokens
#pragma unroll
    for (int m = 0; m < 4; ++m) {
#pragma unroll
      for (int n = 0; n < 4; ++n) {
        const int tok = bm * 128 + wc * 64 + n * 16 + l15;
        if (tok < M) {
          const int w = tok / 49, nt = tok - w * 49;
#pragma unroll
          for (int reg = 0; reg < 4; ++reg) {
            const int ch = bnl * 128 + wr * 64 + m * 16 + lg * 4 + reg;
            const float v = acc[m][n][reg] + bv[ch];
            const int hh = ch >> 5, dd = ch & 31;
            vT_ws[(((size_t)w * 16 + hh) * 32 + dd) * 64 + nt] =
                __float2bfloat16(v);
          }
        }
      }
    }
  } else {
    const float* bb = (cls == 0) ? bk : bq;
    bf16* dp = (cls == 0) ? k_ws : q_ws;
    const float sc = (cls == 0) ? 1.0f : qscale;
#pragma unroll
    for (int m = 0; m < 4; ++m) {
#pragma unroll
      for (int n = 0; n < 4; ++n) {
        const int c = bnl * 128 + wc * 64 + n * 16 + l15;
        const float bvv = bb[c];
        const int hh = c >> 5, dd = c & 31;
#pragma unroll
        for (int reg = 0; reg < 4; ++reg) {
          const int r = bm * 128 + wr * 64 + m * 16 + lg * 4 + reg;
          if (r < M) {
            const int w = r / 49, nt = r - w * 49;
            dp[(((size_t)w * 16 + hh) * 49 + nt) * 32 + dd] =
                __float2bfloat16((acc[m][n][reg] + bvv) * sc);
          }
        }
      }
    }
  }
}

// ---------------- proj GEMM: f32 out [r][512] -------------------------------
__global__ __launch_bounds__(256) void gemm_p(const short* __restrict__ Abf,
                                              const short* __restrict__ Bbf,
                                              const float* __restrict__ bias,
                                              float* __restrict__ dst, int M) {
  __shared__ short As[8192];
  __shared__ short Bs[8192];
  const int nwg = gridDim.x;
  const int t = xcd_swz(blockIdx.x, nwg);
  const int bn = t & 3, bm = t >> 2;
  const int tid = threadIdx.x, lane = tid & 63, wid = tid >> 6;
  const int wr = wid >> 1, wc = wid & 1, l15 = lane & 15, lg = lane >> 4;
  f32x4 acc[4][4];
#pragma unroll
  for (int m = 0; m < 4; ++m)
#pragma unroll
    for (int n = 0; n < 4; ++n) acc[m][n] = (f32x4){0.f, 0.f, 0.f, 0.f};
  const int tr = tid >> 3, tcol = (tid & 7) * 16;
  for (int k0 = 0; k0 < 512; k0 += 64) {
#pragma unroll
    for (int i = 0; i < 4; ++i) {
      gl16((const char*)Abf + (size_t)(bm * 128 + tr + i * 32) * 1024 + k0 * 2 + tcol,
           (char*)As + tid * 16 + i * 4096);
      gl16((const char*)Bbf + (size_t)(bn * 128 + tr + i * 32) * 1024 + k0 * 2 + tcol,
           (char*)Bs + tid * 16 + i * 4096);
    }
    __syncthreads();
#pragma unroll
    for (int s = 0; s < 2; ++s) {
      short8 af[4], bfr[4];
#pragma unroll
      for (int m = 0; m < 4; ++m)
        af[m] = *(const short8*)((char*)As + (wr * 64 + m * 16 + l15) * 128 +
                                 s * 64 + lg * 16);
#pragma unroll
      for (int n = 0; n < 4; ++n)
        bfr[n] = *(const short8*)((char*)Bs + (wc * 64 + n * 16 + l15) * 128 +
                                  s * 64 + lg * 16);
#pragma unroll
      for (int m = 0; m < 4; ++m)
#pragma unroll
        for (int n = 0; n < 4; ++n)
          acc[m][n] = __builtin_amdgcn_mfma_f32_16x16x32_bf16(
              af[m], bfr[n], acc[m][n], 0, 0, 0);
    }
    __syncthreads();
  }
#pragma unroll
  for (int m = 0; m < 4; ++m) {
#pragma unroll
    for (int n = 0; n < 4; ++n) {
      const int c = bn * 128 + wc * 64 + n * 16 + l15;
      const float bvv = bias[c];
#pragma unroll
      for (int reg = 0; reg < 4; ++reg) {
        const int r = bm * 128 + wr * 64 + m * 16 + lg * 4 + reg;
        if (r < M) dst[(size_t)r * 512 + c] = acc[m][n][reg] + bvv;
      }
    }
  }
}

// ---------------- windowed attention: 1 head per wave, no barriers ---------
__global__ __launch_bounds__(256) void attn_win2(
    const bf16* __restrict__ q_ws, const bf16* __restrict__ k_ws,
    const bf16* __restrict__ vT_ws, const float* __restrict__ rpbL,
    const float* __restrict__ maskL, bf16* __restrict__ x_ws, int wstart) {
  __shared__ short sP[4][4096];
  const int tid = threadIdx.x, lane = tid & 63, wid = tid >> 6;
  const int l15 = lane & 15, lg = lane >> 4;
  const int wl = blockIdx.x;
  const int h = blockIdx.y * 4 + wid;
  const int wg = wstart + wl;
  char* Pl = (char*)sP[wid];
  const size_t base = ((size_t)wl * 16 + h) * 1568;
  const short8 z8 = (short8){0, 0, 0, 0, 0, 0, 0, 0};

  short8 qf[4], kf[4];
#pragma unroll
  for (int m = 0; m < 4; ++m) {
    const int r = m * 16 + l15;
    qf[m] = (r < 49) ? *(const short8*)(q_ws + base + r * 32 + lg * 8) : z8;
    kf[m] = (r < 49) ? *(const short8*)(k_ws + base + r * 32 + lg * 8) : z8;
  }
  f32x4 lc[4][4];
#pragma unroll
  for (int m = 0; m < 4; ++m)
#pragma unroll
    for (int n = 0; n < 4; ++n)
      lc[m][n] = __builtin_amdgcn_mfma_f32_16x16x32_bf16(
          qf[m], kf[n], (f32x4){0.f, 0.f, 0.f, 0.f}, 0, 0, 0);

  const f32x4* rbp = (const f32x4*)rpbL + (size_t)h * 1024 + lane;
  const f32x4* mkp = (const f32x4*)maskL + (size_t)(wg & 1023) * 1024 + lane;
#pragma unroll
  for (int m = 0; m < 4; ++m)
#pragma unroll
    for (int n = 0; n < 4; ++n) {
      const int mn = m * 4 + n;
      lc[m][n] += rbp[mn * 64] + mkp[mn * 64];
    }

#pragma unroll
  for (int m = 0; m < 4; ++m) {
#pragma unroll
    for (int reg = 0; reg < 4; ++reg) {
      float vmax = fmaxf(fmaxf(lc[m][0][reg], lc[m][1][reg]),
                         fmaxf(lc[m][2][reg], lc[m][3][reg]));
#pragma unroll
      for (int off = 1; off < 16; off <<= 1)
        vmax = fmaxf(vmax, __shfl_xor(vmax, off, 64));
      float e[4], ssum = 0.f;
#pragma unroll
      for (int n = 0; n < 4; ++n) {
        e[n] = __expf(lc[m][n][reg] - vmax);
        ssum += e[n];
      }
#pragma unroll
      for (int off = 1; off < 16; off <<= 1) ssum += __shfl_xor(ssum, off, 64);
      const float inv = __builtin_amdgcn_rcpf(ssum);
      const int i = m * 16 + lg * 4 + reg;
#pragma unroll
      for (int n = 0; n < 4; ++n) {
        const int cc = n * 16 + l15;
        *(unsigned short*)(Pl + i * 128 + ((2 * cc) ^ ((i & 7) << 4))) =
            f2b(e[n] * inv);
      }
    }
  }

  f32x4 xacc[4][2];
#pragma unroll
  for (int m = 0; m < 4; ++m)
#pragma unroll
    for (int n = 0; n < 2; ++n) xacc[m][n] = (f32x4){0.f, 0.f, 0.f, 0.f};
  const size_t vbase = ((size_t)wl * 16 + h) * 2048;
#pragma unroll
  for (int s = 0; s < 2; ++s) {
    short8 pf[4], vf[2];
#pragma unroll
    for (int m = 0; m < 4; ++m) {
      const int i = m * 16 + l15;
      pf[m] = *(const short8*)(Pl + i * 128 +
                               ((s * 64 + lg * 16) ^ ((i & 7) << 4)));
    }
#pragma unroll
    for (int n = 0; n < 2; ++n) {
      const int dd = n * 16 + l15;
      short8 vv = *(const short8*)(vT_ws + vbase + dd * 64 + s * 32 + lg * 8);
      if (s == 1) {
        if (lg == 3) vv = z8;
        else if (lg == 2) {
          vv[1] = 0; vv[2] = 0; vv[3] = 0; vv[4] = 0;
          vv[5] = 0; vv[6] = 0; vv[7] = 0;
        }
      }
      vf[n] = vv;
    }
#pragma unroll
    for (int m = 0; m < 4; ++m)
#pragma unroll
      for (int n = 0; n < 2; ++n)
        xacc[m][n] = __builtin_amdgcn_mfma_f32_16x16x32_bf16(
            pf[m], vf[n], xacc[m][n], 0, 0, 0);
  }

#pragma unroll
  for (int m = 0; m < 4; ++m)
#pragma unroll
    for (int n = 0; n < 2; ++n)
#pragma unroll
      for (int reg = 0; reg < 4; ++reg) {
        const int i = m * 16 + lg * 4 + reg;
        const int dd = n * 16 + l15;
        *(unsigned short*)(Pl + i * 80 + ((2 * dd) ^ ((i & 3) << 4))) =
            f2b(xacc[m][n][reg]);
      }
#pragma unroll
  for (int g = 0; g < 4; ++g) {
    const int row = g * 16 + (lane >> 2);
    if (row < 49) {
      const short8 xv = *(const short8*)(
          Pl + row * 80 + (((lane & 3) * 16) ^ ((row & 3) << 4)));
      *(short8*)(x_ws + ((size_t)wl * 49 + row) * 512 + h * 32 +
                 (lane & 3) * 8) = xv;
    }
  }
}

extern "C" void kernel_launch(void* const* d_in, const int* in_sizes, int n_in,
                              void* d_out, int out_size, void* d_ws,
                              size_t ws_size, hipStream_t stream) {
  const float* lf   = (const float*)d_in[0];
  const float* gfx  = (const float*)d_in[1];
  const float* mask = (const float*)d_in[2];
  const float* btab = (const float*)d_in[3];
  const float* Wk = (const float*)d_in[4];  const float* bk = (const float*)d_in[5];
  const float* Wq = (const float*)d_in[6];  const float* bq = (const float*)d_in[7];
  const float* Wv = (const float*)d_in[8];  const float* bv = (const float*)d_in[9];
  const float* Wp = (const float*)d_in[10]; const float* bp = (const float*)d_in[11];
  float* out = (float*)d_out;

  char* ws = (char*)d_ws;
  short* wbf = (short*)ws;  // 4 x 512x512 bf16 = 2 MB
  size_t off = (size_t)4 * 262144 * 2;
  float* rpbL = (float*)(ws + off); off += (size_t)16 * 4096 * 4;     // 256 KB
  float* maskL = (float*)(ws + off); off += (size_t)1024 * 4096 * 4;  // 16 MB

  const size_t perw = 2 * 49 * 1024 + 2 * 50176 + 65536;  // 266240 B/window
  size_t avail = (ws_size > off + 65536) ? ws_size - off - 65536 : 0;
  int CH = (int)((avail > 300000) ? (avail - 262144) / perw : 1);
  if (CH > 4096) CH = 4096;
  if (CH < 1) CH = 1;
  const int RWS = ((CH * 49 + 127) / 128) * 128;

  short* Al = (short*)(ws + off); off += (size_t)RWS * 1024;
  short* Ag = (short*)(ws + off); off += (size_t)RWS * 1024;
  bf16* q_ws = (bf16*)(ws + off); off += (size_t)CH * 50176;
  bf16* k_ws = (bf16*)(ws + off); off += (size_t)CH * 50176;
  bf16* vT_ws = (bf16*)(ws + off); off += (size_t)CH * 65536;
  bf16* x_ws = (bf16*)Al;  // alias: Al dead after gemm_kqv

  cvt_w_kernel<<<256, 256, 0, stream>>>(Wk, Wq, Wv, Wp, (bf16*)wbf);
  prep_rpbL<<<64, 256, 0, stream>>>(btab, rpbL);
  prep_maskL<<<4096, 256, 0, stream>>>(mask, maskL);

  const float qscale = 0.17677669529663687f;  // 1/sqrt(32)
  for (int wstart = 0; wstart < 4096; wstart += CH) {
    const int nwin = (4096 - wstart < CH) ? (4096 - wstart) : CH;
    const int M = nwin * 49;
    const int gy = (M + 127) / 128;
    const int cg = (M * 64 + 255) / 256;
    cvt_a<<<cg, 256, 0, stream>>>(lf + (size_t)wstart * 25088, Al, M);
    cvt_a<<<cg, 256, 0, stream>>>(gfx + (size_t)wstart * 25088, Ag, M);
    gemm_kqv<<<12 * gy, 256, 0, stream>>>(Al, Ag, wbf, bk, bq, bv, qscale,
                                          k_ws, q_ws, vT_ws, M);
    attn_win2<<<dim3(nwin, 4), 256, 0, stream>>>(q_ws, k_ws, vT_ws, rpbL,
                                                 maskL, x_ws, wstart);
    gemm_p<<<4 * gy, 256, 0, stream>>>((const short*)x_ws, wbf + 3 * 262144,
                                       bp, out + (size_t)wstart * 25088, M);
  }
}

// Round 4
// 1550.082 us; speedup vs baseline: 1.3999x; 1.0498x over previous
//
#include <hip/hip_runtime.h>
#include <hip/hip_bf16.h>

typedef __hip_bfloat16 bf16;
typedef __attribute__((ext_vector_type(4))) float f32x4;
typedef __attribute__((ext_vector_type(8))) short short8;
typedef __attribute__((ext_vector_type(4))) short short4v;

#define NEGBIG (-3.0e38f)

__device__ __forceinline__ unsigned short f2b(float x) {
  union { float f; unsigned int u; } v; v.f = x;
  unsigned int r = v.u + 0x7fffu + ((v.u >> 16) & 1u);
  return (unsigned short)(r >> 16);
}

__device__ __forceinline__ void gl16(const void* g, void* l) {
  __builtin_amdgcn_global_load_lds(
      (const __attribute__((address_space(1))) unsigned int*)g,
      (__attribute__((address_space(3))) unsigned int*)l, 16, 0, 0);
}

// bijective XCD-grouping swizzle (m204): contiguous tile range per XCD
__device__ __forceinline__ int xcd_swz(int orig, int nwg) {
  const int q = nwg >> 3, r = nwg & 7;
  const int xcd = orig & 7;
  const int base = (xcd < r) ? xcd * (q + 1) : r * (q + 1) + (xcd - r) * q;
  return base + (orig >> 3);
}

// stage 128x64-bf16 tiles A,B into LDS. LDS layout linear; global source
// column slot is XOR-permuted by row&7 so a swizzled ds_read is conflict-free
// (rule #21: linear dest + inverse-swizzled source + swizzled read).
__device__ __forceinline__ void stage_tiles(const char* Ab, const char* Bb,
                                            char* Asb, char* Bsb, int arow0,
                                            int brow0, int k0) {
  const int tid = threadIdx.x;
#pragma unroll
  for (int i = 0; i < 4; ++i) {
    const int c = tid + 256 * i;
    const int row = c >> 3;
    const int scol = ((c & 7) ^ (row & 7)) << 4;
    gl16(Ab + (size_t)(arow0 + row) * 1024 + k0 * 2 + scol, Asb + c * 16);
    gl16(Bb + (size_t)(brow0 + row) * 1024 + k0 * 2 + scol, Bsb + c * 16);
  }
}

// ---------------- weight f32 -> bf16 (row-major) ----------------
__global__ __launch_bounds__(256) void cvt_w_kernel(
    const float* __restrict__ a, const float* __restrict__ b,
    const float* __restrict__ c, const float* __restrict__ d,
    bf16* __restrict__ dst) {
  const int t = blockIdx.x * 256 + threadIdx.x;
  const float* srcs[4] = {a, b, c, d};
#pragma unroll
  for (int w = 0; w < 4; ++w) {
    const f32x4 v = *(const f32x4*)(srcs[w] + (size_t)t * 4);
    short4v o;
    o[0] = (short)f2b(v[0]); o[1] = (short)f2b(v[1]);
    o[2] = (short)f2b(v[2]); o[3] = (short)f2b(v[3]);
    *(short4v*)((short*)dst + (size_t)w * 262144 + (size_t)t * 4) = o;
  }
}

// ---------------- activation f32 -> bf16 (row-major [M][512]) -------------
__global__ __launch_bounds__(256) void cvt_a(const float* __restrict__ src,
                                             short* __restrict__ dst, int M) {
  const int g = blockIdx.x * 256 + threadIdx.x;
  const int row = g >> 6, k8 = g & 63;
  if (row >= M) return;
  const float* sp = src + (size_t)row * 512 + k8 * 8;
  const f32x4 lo = *(const f32x4*)sp;
  const f32x4 hi = *(const f32x4*)(sp + 4);
  short8 u;
  u[0] = (short)f2b(lo[0]); u[1] = (short)f2b(lo[1]);
  u[2] = (short)f2b(lo[2]); u[3] = (short)f2b(lo[3]);
  u[4] = (short)f2b(hi[0]); u[5] = (short)f2b(hi[1]);
  u[6] = (short)f2b(hi[2]); u[7] = (short)f2b(hi[3]);
  *(short8*)(dst + (size_t)row * 512 + k8 * 8) = u;
}

// ---- bias table -> per-(head, frag-element) layout, pads = NEGBIG ----
__global__ __launch_bounds__(256) void prep_rpbL(const float* __restrict__ btab,
                                                 float* __restrict__ rpbL) {
  const int g = blockIdx.x * 256 + threadIdx.x;
  const int lane = g & 63, mn = (g >> 6) & 15, h = g >> 10;
  const int m = mn >> 2, n = mn & 3, l15 = lane & 15, lg = lane >> 4;
  const int cc = n * 16 + l15;
  const int aj = cc / 7, bj = cc % 7;
  f32x4 o;
#pragma unroll
  for (int reg = 0; reg < 4; ++reg) {
    const int i = m * 16 + lg * 4 + reg;
    if (i < 49 && cc < 49) {
      const int t = (i / 7 - aj + 6) * 13 + (i % 7 - bj + 6);
      o[reg] = btab[t * 16 + h];
    } else {
      o[reg] = NEGBIG;
    }
  }
  ((f32x4*)rpbL)[g] = o;
}

// ---- mask -> per-(window, frag-element) layout, pads = 0 ----
__global__ __launch_bounds__(256) void prep_maskL(const float* __restrict__ mask,
                                                  float* __restrict__ maskL) {
  const int g = blockIdx.x * 256 + threadIdx.x;
  const int lane = g & 63, mn = (g >> 6) & 15, wm = g >> 10;
  const int m = mn >> 2, n = mn & 3, l15 = lane & 15, lg = lane >> 4;
  const int cc = n * 16 + l15;
  f32x4 o;
#pragma unroll
  for (int reg = 0; reg < 4; ++reg) {
    const int i = m * 16 + lg * 4 + reg;
    o[reg] = (i < 49 && cc < 49) ? mask[(size_t)wm * 2401 + i * 49 + cc] : 0.f;
  }
  ((f32x4*)maskL)[g] = o;
}

// ---------------- fused KQV GEMM --------------------------------------------
// 1-D grid of 12*gy blocks, XCD-swizzled; bn class: 0..3=K, 4..7=Q, 8..11=V^T.
// Double-buffered LDS (one barrier per K-step), swizzled staging/reads.
__global__ __launch_bounds__(256) void gemm_kqv(
    const short* __restrict__ Al, const short* __restrict__ Ag,
    const short* __restrict__ wbf, const float* __restrict__ bk,
    const float* __restrict__ bq, const float* __restrict__ bv, float qscale,
    bf16* __restrict__ k_ws, bf16* __restrict__ q_ws, bf16* __restrict__ vT_ws,
    int M) {
  __shared__ short As[16384];  // 2 x [128 rows][64 k] bf16
  __shared__ short Bs[16384];
  const int nwg = gridDim.x;
  const int t = xcd_swz(blockIdx.x, nwg);
  const int bn = t % 12, bm = t / 12;
  const int cls = bn >> 2, bnl = bn & 3;
  const int tid = threadIdx.x, lane = tid & 63, wid = tid >> 6;
  const int wr = wid >> 1, wc = wid & 1, l15 = lane & 15, lg = lane >> 4;
  const char* Ab = (const char*)((cls == 1) ? Ag : Al);
  const char* Bb = (const char*)(wbf + (size_t)cls * 262144);

  f32x4 acc[4][4];
#pragma unroll
  for (int m = 0; m < 4; ++m)
#pragma unroll
    for (int n = 0; n < 4; ++n) acc[m][n] = (f32x4){0.f, 0.f, 0.f, 0.f};

  stage_tiles(Ab, Bb, (char*)As, (char*)Bs, bm * 128, bnl * 128, 0);
  __syncthreads();

  for (int kt = 0; kt < 8; ++kt) {
    const int cur = kt & 1;
    if (kt < 7)
      stage_tiles(Ab, Bb, (char*)As + (cur ^ 1) * 16384,
                  (char*)Bs + (cur ^ 1) * 16384, bm * 128, bnl * 128,
                  (kt + 1) * 64);
    const char* fa =
        ((cls == 2) ? (const char*)Bs : (const char*)As) + cur * 16384;
    const char* fb =
        ((cls == 2) ? (const char*)As : (const char*)Bs) + cur * 16384;
#pragma unroll
    for (int s = 0; s < 2; ++s) {
      short8 af[4], bfr[4];
#pragma unroll
      for (int m = 0; m < 4; ++m) {
        const int r = wr * 64 + m * 16 + l15;
        af[m] = *(const short8*)(fa + r * 128 +
                                 ((s * 64 + lg * 16) ^ ((r & 7) << 4)));
      }
#pragma unroll
      for (int n = 0; n < 4; ++n) {
        const int r = wc * 64 + n * 16 + l15;
        bfr[n] = *(const short8*)(fb + r * 128 +
                                  ((s * 64 + lg * 16) ^ ((r & 7) << 4)));
      }
#pragma unroll
      for (int m = 0; m < 4; ++m)
#pragma unroll
        for (int n = 0; n < 4; ++n)
          acc[m][n] = __builtin_amdgcn_mfma_f32_16x16x32_bf16(
              af[m], bfr[n], acc[m][n], 0, 0, 0);
    }
    __syncthreads();
  }

  if (cls == 2) {  // V^T epilogue: rows=channels, cols=tokens
#pragma unroll
    for (int m = 0; m < 4; ++m) {
#pragma unroll
      for (int n = 0; n < 4; ++n) {
        const int tok = bm * 128 + wc * 64 + n * 16 + l15;
        if (tok < M) {
          const int w = tok / 49, nt = tok - w * 49;
#pragma unroll
          for (int reg = 0; reg < 4; ++reg) {
            const int ch = bnl * 128 + wr * 64 + m * 16 + lg * 4 + reg;
            const float v = acc[m][n][reg] + bv[ch];
            const int hh = ch >> 5, dd = ch & 31;
            vT_ws[(((size_t)w * 16 + hh) * 32 + dd) * 64 + nt] =
                __float2bfloat16(v);
          }
        }
      }
    }
  } else {
    const float* bb = (cls == 0) ? bk : bq;
    bf16* dp = (cls == 0) ? k_ws : q_ws;
    const float sc = (cls == 0) ? 1.0f : qscale;
#pragma unroll
    for (int m = 0; m < 4; ++m) {
#pragma unroll
      for (int n = 0; n < 4; ++n) {
        const int c = bnl * 128 + wc * 64 + n * 16 + l15;
        const float bvv = bb[c];
        const int hh = c >> 5, dd = c & 31;
#pragma unroll
        for (int reg = 0; reg < 4; ++reg) {
          const int r = bm * 128 + wr * 64 + m * 16 + lg * 4 + reg;
          if (r < M) {
            const int w = r / 49, nt = r - w * 49;
            dp[(((size_t)w * 16 + hh) * 49 + nt) * 32 + dd] =
                __float2bfloat16((acc[m][n][reg] + bvv) * sc);
          }
        }
      }
    }
  }
}

// ---------------- proj GEMM: f32 out [r][512] -------------------------------
__global__ __launch_bounds__(256) void gemm_p(const short* __restrict__ Abf,
                                              const short* __restrict__ Bbf,
                                              const float* __restrict__ bias,
                                              float* __restrict__ dst, int M) {
  __shared__ short As[16384];
  __shared__ short Bs[16384];
  const int nwg = gridDim.x;
  const int t = xcd_swz(blockIdx.x, nwg);
  const int bn = t & 3, bm = t >> 2;
  const int tid = threadIdx.x, lane = tid & 63, wid = tid >> 6;
  const int wr = wid >> 1, wc = wid & 1, l15 = lane & 15, lg = lane >> 4;
  f32x4 acc[4][4];
#pragma unroll
  for (int m = 0; m < 4; ++m)
#pragma unroll
    for (int n = 0; n < 4; ++n) acc[m][n] = (f32x4){0.f, 0.f, 0.f, 0.f};

  stage_tiles((const char*)Abf, (const char*)Bbf, (char*)As, (char*)Bs,
              bm * 128, bn * 128, 0);
  __syncthreads();

  for (int kt = 0; kt < 8; ++kt) {
    const int cur = kt & 1;
    if (kt < 7)
      stage_tiles((const char*)Abf, (const char*)Bbf,
                  (char*)As + (cur ^ 1) * 16384, (char*)Bs + (cur ^ 1) * 16384,
                  bm * 128, bn * 128, (kt + 1) * 64);
    const char* fa = (const char*)As + cur * 16384;
    const char* fb = (const char*)Bs + cur * 16384;
#pragma unroll
    for (int s = 0; s < 2; ++s) {
      short8 af[4], bfr[4];
#pragma unroll
      for (int m = 0; m < 4; ++m) {
        const int r = wr * 64 + m * 16 + l15;
        af[m] = *(const short8*)(fa + r * 128 +
                                 ((s * 64 + lg * 16) ^ ((r & 7) << 4)));
      }
#pragma unroll
      for (int n = 0; n < 4; ++n) {
        const int r = wc * 64 + n * 16 + l15;
        bfr[n] = *(const short8*)(fb + r * 128 +
                                  ((s * 64 + lg * 16) ^ ((r & 7) << 4)));
      }
#pragma unroll
      for (int m = 0; m < 4; ++m)
#pragma unroll
        for (int n = 0; n < 4; ++n)
          acc[m][n] = __builtin_amdgcn_mfma_f32_16x16x32_bf16(
              af[m], bfr[n], acc[m][n], 0, 0, 0);
    }
    __syncthreads();
  }
#pragma unroll
  for (int m = 0; m < 4; ++m) {
#pragma unroll
    for (int n = 0; n < 4; ++n) {
      const int c = bn * 128 + wc * 64 + n * 16 + l15;
      const float bvv = bias[c];
#pragma unroll
      for (int reg = 0; reg < 4; ++reg) {
        const int r = bm * 128 + wr * 64 + m * 16 + lg * 4 + reg;
        if (r < M) dst[(size_t)r * 512 + c] = acc[m][n][reg] + bvv;
      }
    }
  }
}

// ---------------- windowed attention: 1 head per wave, no barriers ---------
__global__ __launch_bounds__(256) void attn_win2(
    const bf16* __restrict__ q_ws, const bf16* __restrict__ k_ws,
    const bf16* __restrict__ vT_ws, const float* __restrict__ rpbL,
    const float* __restrict__ maskL, bf16* __restrict__ x_ws, int wstart) {
  __shared__ short sP[4][4096];
  const int tid = threadIdx.x, lane = tid & 63, wid = tid >> 6;
  const int l15 = lane & 15, lg = lane >> 4;
  const int wl = blockIdx.x;
  const int h = blockIdx.y * 4 + wid;
  const int wg = wstart + wl;
  char* Pl = (char*)sP[wid];
  const size_t base = ((size_t)wl * 16 + h) * 1568;
  const short8 z8 = (short8){0, 0, 0, 0, 0, 0, 0, 0};

  short8 qf[4], kf[4];
#pragma unroll
  for (int m = 0; m < 4; ++m) {
    const int r = m * 16 + l15;
    qf[m] = (r < 49) ? *(const short8*)(q_ws + base + r * 32 + lg * 8) : z8;
    kf[m] = (r < 49) ? *(const short8*)(k_ws + base + r * 32 + lg * 8) : z8;
  }
  f32x4 lc[4][4];
#pragma unroll
  for (int m = 0; m < 4; ++m)
#pragma unroll
    for (int n = 0; n < 4; ++n)
      lc[m][n] = __builtin_amdgcn_mfma_f32_16x16x32_bf16(
          qf[m], kf[n], (f32x4){0.f, 0.f, 0.f, 0.f}, 0, 0, 0);

  const f32x4* rbp = (const f32x4*)rpbL + (size_t)h * 1024 + lane;
  const f32x4* mkp = (const f32x4*)maskL + (size_t)(wg & 1023) * 1024 + lane;
#pragma unroll
  for (int m = 0; m < 4; ++m)
#pragma unroll
    for (int n = 0; n < 4; ++n) {
      const int mn = m * 4 + n;
      lc[m][n] += rbp[mn * 64] + mkp[mn * 64];
    }

#pragma unroll
  for (int m = 0; m < 4; ++m) {
#pragma unroll
    for (int reg = 0; reg < 4; ++reg) {
      float vmax = fmaxf(fmaxf(lc[m][0][reg], lc[m][1][reg]),
                         fmaxf(lc[m][2][reg], lc[m][3][reg]));
#pragma unroll
      for (int off = 1; off < 16; off <<= 1)
        vmax = fmaxf(vmax, __shfl_xor(vmax, off, 64));
      float e[4], ssum = 0.f;
#pragma unroll
      for (int n = 0; n < 4; ++n) {
        e[n] = __expf(lc[m][n][reg] - vmax);
        ssum += e[n];
      }
#pragma unroll
      for (int off = 1; off < 16; off <<= 1) ssum += __shfl_xor(ssum, off, 64);
      const float inv = __builtin_amdgcn_rcpf(ssum);
      const int i = m * 16 + lg * 4 + reg;
#pragma unroll
      for (int n = 0; n < 4; ++n) {
        const int cc = n * 16 + l15;
        *(unsigned short*)(Pl + i * 128 + ((2 * cc) ^ ((i & 7) << 4))) =
            f2b(e[n] * inv);
      }
    }
  }

  f32x4 xacc[4][2];
#pragma unroll
  for (int m = 0; m < 4; ++m)
#pragma unroll
    for (int n = 0; n < 2; ++n) xacc[m][n] = (f32x4){0.f, 0.f, 0.f, 0.f};
  const size_t vbase = ((size_t)wl * 16 + h) * 2048;
#pragma unroll
  for (int s = 0; s < 2; ++s) {
    short8 pf[4], vf[2];
#pragma unroll
    for (int m = 0; m < 4; ++m) {
      const int i = m * 16 + l15;
      pf[m] = *(const short8*)(Pl + i * 128 +
                               ((s * 64 + lg * 16) ^ ((i & 7) << 4)));
    }
#pragma unroll
    for (int n = 0; n < 2; ++n) {
      const int dd = n * 16 + l15;
      short8 vv = *(const short8*)(vT_ws + vbase + dd * 64 + s * 32 + lg * 8);
      if (s == 1) {
        if (lg == 3) vv = z8;
        else if (lg == 2) {
          vv[1] = 0; vv[2] = 0; vv[3] = 0; vv[4] = 0;
          vv[5] = 0; vv[6] = 0; vv[7] = 0;
        }
      }
      vf[n] = vv;
    }
#pragma unroll
    for (int m = 0; m < 4; ++m)
#pragma unroll
      for (int n = 0; n < 2; ++n)
        xacc[m][n] = __builtin_amdgcn_mfma_f32_16x16x32_bf16(
            pf[m], vf[n], xacc[m][n], 0, 0, 0);
  }

#pragma unroll
  for (int m = 0; m < 4; ++m)
#pragma unroll
    for (int n = 0; n < 2; ++n)
#pragma unroll
      for (int reg = 0; reg < 4; ++reg) {
        const int i = m * 16 + lg * 4 + reg;
        const int dd = n * 16 + l15;
        *(unsigned short*)(Pl + i * 80 + ((2 * dd) ^ ((i & 3) << 4))) =
            f2b(xacc[m][n][reg]);
      }
#pragma unroll
  for (int g = 0; g < 4; ++g) {
    const int row = g * 16 + (lane >> 2);
    if (row < 49) {
      const short8 xv = *(const short8*)(
          Pl + row * 80 + (((lane & 3) * 16) ^ ((row & 3) << 4)));
      *(short8*)(x_ws + ((size_t)wl * 49 + row) * 512 + h * 32 +
                 (lane & 3) * 8) = xv;
    }
  }
}

extern "C" void kernel_launch(void* const* d_in, const int* in_sizes, int n_in,
                              void* d_out, int out_size, void* d_ws,
                              size_t ws_size, hipStream_t stream) {
  const float* lf   = (const float*)d_in[0];
  const float* gfx  = (const float*)d_in[1];
  const float* mask = (const float*)d_in[2];
  const float* btab = (const float*)d_in[3];
  const float* Wk = (const float*)d_in[4];  const float* bk = (const float*)d_in[5];
  const float* Wq = (const float*)d_in[6];  const float* bq = (const float*)d_in[7];
  const float* Wv = (const float*)d_in[8];  const float* bv = (const float*)d_in[9];
  const float* Wp = (const float*)d_in[10]; const float* bp = (const float*)d_in[11];
  float* out = (float*)d_out;

  char* ws = (char*)d_ws;
  short* wbf = (short*)ws;  // 4 x 512x512 bf16 = 2 MB
  size_t off = (size_t)4 * 262144 * 2;
  float* rpbL = (float*)(ws + off); off += (size_t)16 * 4096 * 4;     // 256 KB
  float* maskL = (float*)(ws + off); off += (size_t)1024 * 4096 * 4;  // 16 MB

  const size_t perw = 2 * 49 * 1024 + 2 * 50176 + 65536;  // 266240 B/window
  size_t avail = (ws_size > off + 65536) ? ws_size - off - 65536 : 0;
  int CH = (int)((avail > 300000) ? (avail - 262144) / perw : 1);
  if (CH > 4096) CH = 4096;
  if (CH < 1) CH = 1;
  const int RWS = ((CH * 49 + 127) / 128) * 128;

  short* Al = (short*)(ws + off); off += (size_t)RWS * 1024;
  short* Ag = (short*)(ws + off); off += (size_t)RWS * 1024;
  bf16* q_ws = (bf16*)(ws + off); off += (size_t)CH * 50176;
  bf16* k_ws = (bf16*)(ws + off); off += (size_t)CH * 50176;
  bf16* vT_ws = (bf16*)(ws + off); off += (size_t)CH * 65536;
  bf16* x_ws = (bf16*)Al;  // alias: Al dead after gemm_kqv

  cvt_w_kernel<<<256, 256, 0, stream>>>(Wk, Wq, Wv, Wp, (bf16*)wbf);
  prep_rpbL<<<64, 256, 0, stream>>>(btab, rpbL);
  prep_maskL<<<4096, 256, 0, stream>>>(mask, maskL);

  const float qscale = 0.17677669529663687f;  // 1/sqrt(32)
  for (int wstart = 0; wstart < 4096; wstart += CH) {
    const int nwin = (4096 - wstart < CH) ? (4096 - wstart) : CH;
    const int M = nwin * 49;
    const int gy = (M + 127) / 128;
    const int cg = (M * 64 + 255) / 256;
    cvt_a<<<cg, 256, 0, stream>>>(lf + (size_t)wstart * 25088, Al, M);
    cvt_a<<<cg, 256, 0, stream>>>(gfx + (size_t)wstart * 25088, Ag, M);
    gemm_kqv<<<12 * gy, 256, 0, stream>>>(Al, Ag, wbf, bk, bq, bv, qscale,
                                          k_ws, q_ws, vT_ws, M);
    attn_win2<<<dim3(nwin, 4), 256, 0, stream>>>(q_ws, k_ws, vT_ws, rpbL,
                                                 maskL, x_ws, wstart);
    gemm_p<<<4 * gy, 256, 0, stream>>>((const short*)x_ws, wbf + 3 * 262144,
                                       bp, out + (size_t)wstart * 25088, M);
  }
}

// Round 5
// 1326.361 us; speedup vs baseline: 1.6360x; 1.1687x over previous
//
#include <hip/hip_runtime.h>
#include <hip/hip_bf16.h>

typedef __hip_bfloat16 bf16;
typedef __attribute__((ext_vector_type(4))) float f32x4;
typedef __attribute__((ext_vector_type(8))) short short8;
typedef __attribute__((ext_vector_type(4))) short short4v;

#define NEGBIG (-3.0e38f)

__device__ __forceinline__ unsigned short f2b(float x) {
  union { float f; unsigned int u; } v; v.f = x;
  unsigned int r = v.u + 0x7fffu + ((v.u >> 16) & 1u);
  return (unsigned short)(r >> 16);
}

__device__ __forceinline__ void gl16(const void* g, void* l) {
  __builtin_amdgcn_global_load_lds(
      (const __attribute__((address_space(1))) unsigned int*)g,
      (__attribute__((address_space(3))) unsigned int*)l, 16, 0, 0);
}

// bijective XCD-grouping swizzle (m204): contiguous tile range per XCD
__device__ __forceinline__ int xcd_swz(int orig, int nwg) {
  const int q = nwg >> 3, r = nwg & 7;
  const int xcd = orig & 7;
  const int base = (xcd < r) ? xcd * (q + 1) : r * (q + 1) + (xcd - r) * q;
  return base + (orig >> 3);
}

// stage 128x32-bf16 tiles A,B into LDS (8KB each). LDS dest linear;
// global source 16B-slot is XOR-permuted by (row>>1)&3 so the swizzled
// ds_read below is ~2-way conflict-free (rule #21).
__device__ __forceinline__ void stage32(const char* Ab, const char* Bb,
                                        char* Asb, char* Bsb, int arow0,
                                        int brow0, int k0) {
  const int tid = threadIdx.x;
#pragma unroll
  for (int i = 0; i < 2; ++i) {
    const int g = tid + 256 * i;  // 0..511 -> 16B each
    const int row = g >> 2;       // 0..127
    const int scol = ((g & 3) ^ ((row >> 1) & 3)) << 4;
    gl16(Ab + (size_t)(arow0 + row) * 1024 + k0 * 2 + scol, Asb + g * 16);
    gl16(Bb + (size_t)(brow0 + row) * 1024 + k0 * 2 + scol, Bsb + g * 16);
  }
}

// ---------------- weight f32 -> bf16 (row-major) ----------------
__global__ __launch_bounds__(256) void cvt_w_kernel(
    const float* __restrict__ a, const float* __restrict__ b,
    const float* __restrict__ c, const float* __restrict__ d,
    bf16* __restrict__ dst) {
  const int t = blockIdx.x * 256 + threadIdx.x;
  const float* srcs[4] = {a, b, c, d};
#pragma unroll
  for (int w = 0; w < 4; ++w) {
    const f32x4 v = *(const f32x4*)(srcs[w] + (size_t)t * 4);
    short4v o;
    o[0] = (short)f2b(v[0]); o[1] = (short)f2b(v[1]);
    o[2] = (short)f2b(v[2]); o[3] = (short)f2b(v[3]);
    *(short4v*)((short*)dst + (size_t)w * 262144 + (size_t)t * 4) = o;
  }
}

// ---------------- activation f32 -> bf16 (row-major [M][512]) -------------
__global__ __launch_bounds__(256) void cvt_a(const float* __restrict__ src,
                                             short* __restrict__ dst, int M) {
  const int g = blockIdx.x * 256 + threadIdx.x;
  const int row = g >> 6, k8 = g & 63;
  if (row >= M) return;
  const float* sp = src + (size_t)row * 512 + k8 * 8;
  const f32x4 lo = *(const f32x4*)sp;
  const f32x4 hi = *(const f32x4*)(sp + 4);
  short8 u;
  u[0] = (short)f2b(lo[0]); u[1] = (short)f2b(lo[1]);
  u[2] = (short)f2b(lo[2]); u[3] = (short)f2b(lo[3]);
  u[4] = (short)f2b(hi[0]); u[5] = (short)f2b(hi[1]);
  u[6] = (short)f2b(hi[2]); u[7] = (short)f2b(hi[3]);
  *(short8*)(dst + (size_t)row * 512 + k8 * 8) = u;
}

// ---- bias table -> per-(head, frag-element) layout, pads = NEGBIG ----
__global__ __launch_bounds__(256) void prep_rpbL(const float* __restrict__ btab,
                                                 float* __restrict__ rpbL) {
  const int g = blockIdx.x * 256 + threadIdx.x;
  const int lane = g & 63, mn = (g >> 6) & 15, h = g >> 10;
  const int m = mn >> 2, n = mn & 3, l15 = lane & 15, lg = lane >> 4;
  const int cc = n * 16 + l15;
  const int aj = cc / 7, bj = cc % 7;
  f32x4 o;
#pragma unroll
  for (int reg = 0; reg < 4; ++reg) {
    const int i = m * 16 + lg * 4 + reg;
    if (i < 49 && cc < 49) {
      const int t = (i / 7 - aj + 6) * 13 + (i % 7 - bj + 6);
      o[reg] = btab[t * 16 + h];
    } else {
      o[reg] = NEGBIG;
    }
  }
  ((f32x4*)rpbL)[g] = o;
}

// ---- mask -> per-(window, frag-element) layout, pads = 0 ----
__global__ __launch_bounds__(256) void prep_maskL(const float* __restrict__ mask,
                                                  float* __restrict__ maskL) {
  const int g = blockIdx.x * 256 + threadIdx.x;
  const int lane = g & 63, mn = (g >> 6) & 15, wm = g >> 10;
  const int m = mn >> 2, n = mn & 3, l15 = lane & 15, lg = lane >> 4;
  const int cc = n * 16 + l15;
  f32x4 o;
#pragma unroll
  for (int reg = 0; reg < 4; ++reg) {
    const int i = m * 16 + lg * 4 + reg;
    o[reg] = (i < 49 && cc < 49) ? mask[(size_t)wm * 2401 + i * 49 + cc] : 0.f;
  }
  ((f32x4*)maskL)[g] = o;
}

// ---------------- fused KQV GEMM --------------------------------------------
// 1-D grid of 12*gy blocks, XCD-swizzled; bn class: 0..3=K, 4..7=Q, 8..11=V^T.
// BK=32 double-buffered LDS (32KB total -> 4 blocks/CU), swizzled reads.
__global__ __launch_bounds__(256, 4) void gemm_kqv(
    const short* __restrict__ Al, const short* __restrict__ Ag,
    const short* __restrict__ wbf, const float* __restrict__ bk,
    const float* __restrict__ bq, const float* __restrict__ bv, float qscale,
    bf16* __restrict__ k_ws, bf16* __restrict__ q_ws, bf16* __restrict__ vT_ws,
    int M) {
  __shared__ short As[8192];  // 2 x [128 rows][32 k] bf16
  __shared__ short Bs[8192];
  const int nwg = gridDim.x;
  const int t = xcd_swz(blockIdx.x, nwg);
  const int bn = t % 12, bm = t / 12;
  const int cls = bn >> 2, bnl = bn & 3;
  const int tid = threadIdx.x, lane = tid & 63, wid = tid >> 6;
  const int wr = wid >> 1, wc = wid & 1, l15 = lane & 15, lg = lane >> 4;
  const char* Ab = (const char*)((cls == 1) ? Ag : Al);
  const char* Bb = (const char*)(wbf + (size_t)cls * 262144);

  f32x4 acc[4][4];
#pragma unroll
  for (int m = 0; m < 4; ++m)
#pragma unroll
    for (int n = 0; n < 4; ++n) acc[m][n] = (f32x4){0.f, 0.f, 0.f, 0.f};

  stage32(Ab, Bb, (char*)As, (char*)Bs, bm * 128, bnl * 128, 0);
  __syncthreads();

  for (int kt = 0; kt < 16; ++kt) {
    const int cur = kt & 1;
    if (kt < 15)
      stage32(Ab, Bb, (char*)As + (cur ^ 1) * 8192,
              (char*)Bs + (cur ^ 1) * 8192, bm * 128, bnl * 128,
              (kt + 1) * 32);
    const char* fa =
        ((cls == 2) ? (const char*)Bs : (const char*)As) + cur * 8192;
    const char* fb =
        ((cls == 2) ? (const char*)As : (const char*)Bs) + cur * 8192;
    short8 af[4], bfr[4];
#pragma unroll
    for (int m = 0; m < 4; ++m) {
      const int r = wr * 64 + m * 16 + l15;
      af[m] = *(const short8*)(fa + r * 64 +
                               ((lg << 4) ^ (((r >> 1) & 3) << 4)));
    }
#pragma unroll
    for (int n = 0; n < 4; ++n) {
      const int r = wc * 64 + n * 16 + l15;
      bfr[n] = *(const short8*)(fb + r * 64 +
                                ((lg << 4) ^ (((r >> 1) & 3) << 4)));
    }
#pragma unroll
    for (int m = 0; m < 4; ++m)
#pragma unroll
      for (int n = 0; n < 4; ++n)
        acc[m][n] = __builtin_amdgcn_mfma_f32_16x16x32_bf16(
            af[m], bfr[n], acc[m][n], 0, 0, 0);
    __syncthreads();
  }

  if (cls == 2) {  // V^T epilogue: rows=channels, cols=tokens
#pragma unroll
    for (int m = 0; m < 4; ++m) {
#pragma unroll
      for (int n = 0; n < 4; ++n) {
        const int tok = bm * 128 + wc * 64 + n * 16 + l15;
        if (tok < M) {
          const int w = tok / 49, nt = tok - w * 49;
#pragma unroll
          for (int reg = 0; reg < 4; ++reg) {
            const int ch = bnl * 128 + wr * 64 + m * 16 + lg * 4 + reg;
            const float v = acc[m][n][reg] + bv[ch];
            const int hh = ch >> 5, dd = ch & 31;
            vT_ws[(((size_t)w * 16 + hh) * 32 + dd) * 64 + nt] =
                __float2bfloat16(v);
          }
        }
      }
    }
  } else {
    const float* bb = (cls == 0) ? bk : bq;
    bf16* dp = (cls == 0) ? k_ws : q_ws;
    const float sc = (cls == 0) ? 1.0f : qscale;
#pragma unroll
    for (int m = 0; m < 4; ++m) {
#pragma unroll
      for (int n = 0; n < 4; ++n) {
        const int c = bnl * 128 + wc * 64 + n * 16 + l15;
        const float bvv = bb[c];
        const int hh = c >> 5, dd = c & 31;
#pragma unroll
        for (int reg = 0; reg < 4; ++reg) {
          const int r = bm * 128 + wr * 64 + m * 16 + lg * 4 + reg;
          if (r < M) {
            const int w = r / 49, nt = r - w * 49;
            dp[(((size_t)w * 16 + hh) * 49 + nt) * 32 + dd] =
                __float2bfloat16((acc[m][n][reg] + bvv) * sc);
          }
        }
      }
    }
  }
}

// ---------------- proj GEMM: f32 out [r][512] -------------------------------
__global__ __launch_bounds__(256, 4) void gemm_p(const short* __restrict__ Abf,
                                                 const short* __restrict__ Bbf,
                                                 const float* __restrict__ bias,
                                                 float* __restrict__ dst,
                                                 int M) {
  __shared__ short As[8192];
  __shared__ short Bs[8192];
  const int nwg = gridDim.x;
  const int t = xcd_swz(blockIdx.x, nwg);
  const int bn = t & 3, bm = t >> 2;
  const int tid = threadIdx.x, lane = tid & 63, wid = tid >> 6;
  const int wr = wid >> 1, wc = wid & 1, l15 = lane & 15, lg = lane >> 4;
  f32x4 acc[4][4];
#pragma unroll
  for (int m = 0; m < 4; ++m)
#pragma unroll
    for (int n = 0; n < 4; ++n) acc[m][n] = (f32x4){0.f, 0.f, 0.f, 0.f};

  stage32((const char*)Abf, (const char*)Bbf, (char*)As, (char*)Bs, bm * 128,
          bn * 128, 0);
  __syncthreads();

  for (int kt = 0; kt < 16; ++kt) {
    const int cur = kt & 1;
    if (kt < 15)
      stage32((const char*)Abf, (const char*)Bbf, (char*)As + (cur ^ 1) * 8192,
              (char*)Bs + (cur ^ 1) * 8192, bm * 128, bn * 128, (kt + 1) * 32);
    const char* fa = (const char*)As + cur * 8192;
    const char* fb = (const char*)Bs + cur * 8192;
    short8 af[4], bfr[4];
#pragma unroll
    for (int m = 0; m < 4; ++m) {
      const int r = wr * 64 + m * 16 + l15;
      af[m] = *(const short8*)(fa + r * 64 +
                               ((lg << 4) ^ (((r >> 1) & 3) << 4)));
    }
#pragma unroll
    for (int n = 0; n < 4; ++n) {
      const int r = wc * 64 + n * 16 + l15;
      bfr[n] = *(const short8*)(fb + r * 64 +
                                ((lg << 4) ^ (((r >> 1) & 3) << 4)));
    }
#pragma unroll
    for (int m = 0; m < 4; ++m)
#pragma unroll
      for (int n = 0; n < 4; ++n)
        acc[m][n] = __builtin_amdgcn_mfma_f32_16x16x32_bf16(
            af[m], bfr[n], acc[m][n], 0, 0, 0);
    __syncthreads();
  }
#pragma unroll
  for (int m = 0; m < 4; ++m) {
#pragma unroll
    for (int n = 0; n < 4; ++n) {
      const int c = bn * 128 + wc * 64 + n * 16 + l15;
      const float bvv = bias[c];
#pragma unroll
      for (int reg = 0; reg < 4; ++reg) {
        const int r = bm * 128 + wr * 64 + m * 16 + lg * 4 + reg;
        if (r < M) dst[(size_t)r * 512 + c] = acc[m][n][reg] + bvv;
      }
    }
  }
}

// ---------------- windowed attention: 1 head per wave, no barriers ---------
__global__ __launch_bounds__(256) void attn_win2(
    const bf16* __restrict__ q_ws, const bf16* __restrict__ k_ws,
    const bf16* __restrict__ vT_ws, const float* __restrict__ rpbL,
    const float* __restrict__ maskL, bf16* __restrict__ x_ws, int wstart) {
  __shared__ short sP[4][4096];
  const int tid = threadIdx.x, lane = tid & 63, wid = tid >> 6;
  const int l15 = lane & 15, lg = lane >> 4;
  const int wl = blockIdx.x;
  const int h = blockIdx.y * 4 + wid;
  const int wg = wstart + wl;
  char* Pl = (char*)sP[wid];
  const size_t base = ((size_t)wl * 16 + h) * 1568;
  const short8 z8 = (short8){0, 0, 0, 0, 0, 0, 0, 0};

  short8 qf[4], kf[4];
#pragma unroll
  for (int m = 0; m < 4; ++m) {
    const int r = m * 16 + l15;
    qf[m] = (r < 49) ? *(const short8*)(q_ws + base + r * 32 + lg * 8) : z8;
    kf[m] = (r < 49) ? *(const short8*)(k_ws + base + r * 32 + lg * 8) : z8;
  }
  f32x4 lc[4][4];
#pragma unroll
  for (int m = 0; m < 4; ++m)
#pragma unroll
    for (int n = 0; n < 4; ++n)
      lc[m][n] = __builtin_amdgcn_mfma_f32_16x16x32_bf16(
          qf[m], kf[n], (f32x4){0.f, 0.f, 0.f, 0.f}, 0, 0, 0);

  const f32x4* rbp = (const f32x4*)rpbL + (size_t)h * 1024 + lane;
  const f32x4* mkp = (const f32x4*)maskL + (size_t)(wg & 1023) * 1024 + lane;
#pragma unroll
  for (int m = 0; m < 4; ++m)
#pragma unroll
    for (int n = 0; n < 4; ++n) {
      const int mn = m * 4 + n;
      lc[m][n] += rbp[mn * 64] + mkp[mn * 64];
    }

#pragma unroll
  for (int m = 0; m < 4; ++m) {
#pragma unroll
    for (int reg = 0; reg < 4; ++reg) {
      float vmax = fmaxf(fmaxf(lc[m][0][reg], lc[m][1][reg]),
                         fmaxf(lc[m][2][reg], lc[m][3][reg]));
#pragma unroll
      for (int off = 1; off < 16; off <<= 1)
        vmax = fmaxf(vmax, __shfl_xor(vmax, off, 64));
      float e[4], ssum = 0.f;
#pragma unroll
      for (int n = 0; n < 4; ++n) {
        e[n] = __expf(lc[m][n][reg] - vmax);
        ssum += e[n];
      }
#pragma unroll
      for (int off = 1; off < 16; off <<= 1) ssum += __shfl_xor(ssum, off, 64);
      const float inv = __builtin_amdgcn_rcpf(ssum);
      const int i = m * 16 + lg * 4 + reg;
#pragma unroll
      for (int n = 0; n < 4; ++n) {
        const int cc = n * 16 + l15;
        *(unsigned short*)(Pl + i * 128 + ((2 * cc) ^ ((i & 7) << 4))) =
            f2b(e[n] * inv);
      }
    }
  }

  f32x4 xacc[4][2];
#pragma unroll
  for (int m = 0; m < 4; ++m)
#pragma unroll
    for (int n = 0; n < 2; ++n) xacc[m][n] = (f32x4){0.f, 0.f, 0.f, 0.f};
  const size_t vbase = ((size_t)wl * 16 + h) * 2048;
#pragma unroll
  for (int s = 0; s < 2; ++s) {
    short8 pf[4], vf[2];
#pragma unroll
    for (int m = 0; m < 4; ++m) {
      const int i = m * 16 + l15;
      pf[m] = *(const short8*)(Pl + i * 128 +
                               ((s * 64 + lg * 16) ^ ((i & 7) << 4)));
    }
#pragma unroll
    for (int n = 0; n < 2; ++n) {
      const int dd = n * 16 + l15;
      short8 vv = *(const short8*)(vT_ws + vbase + dd * 64 + s * 32 + lg * 8);
      if (s == 1) {
        if (lg == 3) vv = z8;
        else if (lg == 2) {
          vv[1] = 0; vv[2] = 0; vv[3] = 0; vv[4] = 0;
          vv[5] = 0; vv[6] = 0; vv[7] = 0;
        }
      }
      vf[n] = vv;
    }
#pragma unroll
    for (int m = 0; m < 4; ++m)
#pragma unroll
      for (int n = 0; n < 2; ++n)
        xacc[m][n] = __builtin_amdgcn_mfma_f32_16x16x32_bf16(
            pf[m], vf[n], xacc[m][n], 0, 0, 0);
  }

#pragma unroll
  for (int m = 0; m < 4; ++m)
#pragma unroll
    for (int n = 0; n < 2; ++n)
#pragma unroll
      for (int reg = 0; reg < 4; ++reg) {
        const int i = m * 16 + lg * 4 + reg;
        const int dd = n * 16 + l15;
        *(unsigned short*)(Pl + i * 80 + ((2 * dd) ^ ((i & 3) << 4))) =
            f2b(xacc[m][n][reg]);
      }
#pragma unroll
  for (int g = 0; g < 4; ++g) {
    const int row = g * 16 + (lane >> 2);
    if (row < 49) {
      const short8 xv = *(const short8*)(
          Pl + row * 80 + (((lane & 3) * 16) ^ ((row & 3) << 4)));
      *(short8*)(x_ws + ((size_t)wl * 49 + row) * 512 + h * 32 +
                 (lane & 3) * 8) = xv;
    }
  }
}

extern "C" void kernel_launch(void* const* d_in, const int* in_sizes, int n_in,
                              void* d_out, int out_size, void* d_ws,
                              size_t ws_size, hipStream_t stream) {
  const float* lf   = (const float*)d_in[0];
  const float* gfx  = (const float*)d_in[1];
  const float* mask = (const float*)d_in[2];
  const float* btab = (const float*)d_in[3];
  const float* Wk = (const float*)d_in[4];  const float* bk = (const float*)d_in[5];
  const float* Wq = (const float*)d_in[6];  const float* bq = (const float*)d_in[7];
  const float* Wv = (const float*)d_in[8];  const float* bv = (const float*)d_in[9];
  const float* Wp = (const float*)d_in[10]; const float* bp = (const float*)d_in[11];
  float* out = (float*)d_out;

  char* ws = (char*)d_ws;
  short* wbf = (short*)ws;  // 4 x 512x512 bf16 = 2 MB
  size_t off = (size_t)4 * 262144 * 2;
  float* rpbL = (float*)(ws + off); off += (size_t)16 * 4096 * 4;     // 256 KB
  float* maskL = (float*)(ws + off); off += (size_t)1024 * 4096 * 4;  // 16 MB

  const size_t perw = 2 * 49 * 1024 + 2 * 50176 + 65536;  // 266240 B/window
  size_t avail = (ws_size > off + 65536) ? ws_size - off - 65536 : 0;
  int CH = (int)((avail > 300000) ? (avail - 262144) / perw : 1);
  if (CH > 4096) CH = 4096;
  if (CH < 1) CH = 1;
  const int RWS = ((CH * 49 + 127) / 128) * 128;

  short* Al = (short*)(ws + off); off += (size_t)RWS * 1024;
  short* Ag = (short*)(ws + off); off += (size_t)RWS * 1024;
  bf16* q_ws = (bf16*)(ws + off); off += (size_t)CH * 50176;
  bf16* k_ws = (bf16*)(ws + off); off += (size_t)CH * 50176;
  bf16* vT_ws = (bf16*)(ws + off); off += (size_t)CH * 65536;
  bf16* x_ws = (bf16*)Al;  // alias: Al dead after gemm_kqv

  cvt_w_kernel<<<256, 256, 0, stream>>>(Wk, Wq, Wv, Wp, (bf16*)wbf);
  prep_rpbL<<<64, 256, 0, stream>>>(btab, rpbL);
  prep_maskL<<<4096, 256, 0, stream>>>(mask, maskL);

  const float qscale = 0.17677669529663687f;  // 1/sqrt(32)
  for (int wstart = 0; wstart < 4096; wstart += CH) {
    const int nwin = (4096 - wstart < CH) ? (4096 - wstart) : CH;
    const int M = nwin * 49;
    const int gy = (M + 127) / 128;
    const int cg = (M * 64 + 255) / 256;
    cvt_a<<<cg, 256, 0, stream>>>(lf + (size_t)wstart * 25088, Al, M);
    cvt_a<<<cg, 256, 0, stream>>>(gfx + (size_t)wstart * 25088, Ag, M);
    gemm_kqv<<<12 * gy, 256, 0, stream>>>(Al, Ag, wbf, bk, bq, bv, qscale,
                                          k_ws, q_ws, vT_ws, M);
    attn_win2<<<dim3(nwin, 4), 256, 0, stream>>>(q_ws, k_ws, vT_ws, rpbL,
                                                 maskL, x_ws, wstart);
    gemm_p<<<4 * gy, 256, 0, stream>>>((const short*)x_ws, wbf + 3 * 262144,
                                       bp, out + (size_t)wstart * 25088, M);
  }
}